// Round 1
// baseline (2592.089 us; speedup 1.0000x reference)
//
#include <hip/hip_runtime.h>
#include <hip/hip_bf16.h>
#include <math.h>

#define H 256
#define N0 50000
#define N1 10000
#define N2 4000
#define N3 1024
#define FAN 16

// ---------------- GEMM: Y[m,n] = bias[n] + sum_k X[row(m),k]*W[k,n] ----------------
// 64x64 tile, 256 threads, each thread 4x4. Optional row gather via idx.
__global__ __launch_bounds__(256) void gemm_bias(
    const float* __restrict__ X, const int* __restrict__ idx,
    const float* __restrict__ W, const float* __restrict__ bias,
    float* __restrict__ Y, int M, int K, int N)
{
    __shared__ float As[16][64];   // [k][m]
    __shared__ float Bs[16][64];   // [k][n]
    int tid = threadIdx.x;
    int m0 = blockIdx.x * 64;
    int n0 = blockIdx.y * 64;
    int tx = tid & 15, ty = tid >> 4;
    float acc[4][4] = {};
    for (int k0 = 0; k0 < K; k0 += 16) {
        #pragma unroll
        for (int i = 0; i < 4; i++) {
            int lin = tid + i * 256;      // 0..1023
            // A: 64 rows x 16 k, consecutive tid -> consecutive k (64B segments)
            int ka = lin & 15;
            int ma = lin >> 4;
            float vA = 0.f;
            int gm = m0 + ma;
            if (gm < M) {
                int row = idx ? idx[gm] : gm;
                vA = X[(long)row * K + k0 + ka];
            }
            As[ka][ma] = vA;
            // B: 16 k x 64 n, consecutive tid -> consecutive n
            int nb = lin & 63;
            int kb = lin >> 6;
            Bs[kb][nb] = W[(long)(k0 + kb) * N + n0 + nb];
        }
        __syncthreads();
        #pragma unroll
        for (int kk = 0; kk < 16; kk++) {
            float a[4], b[4];
            #pragma unroll
            for (int i = 0; i < 4; i++) a[i] = As[kk][ty * 4 + i];
            #pragma unroll
            for (int j = 0; j < 4; j++) b[j] = Bs[kk][tx * 4 + j];
            #pragma unroll
            for (int i = 0; i < 4; i++)
                #pragma unroll
                for (int j = 0; j < 4; j++)
                    acc[i][j] += a[i] * b[j];
        }
        __syncthreads();
    }
    #pragma unroll
    for (int i = 0; i < 4; i++) {
        int gm = m0 + ty * 4 + i;
        if (gm >= M) continue;
        #pragma unroll
        for (int j = 0; j < 4; j++) {
            int gn = n0 + tx * 4 + j;
            Y[(long)gm * N + gn] = acc[i][j] + bias[gn];
        }
    }
}

// ---------------- Attention: one wave per (dst,head), 16 fixed edges ----------------
template<int CPL>   // channels per lane = ch/64
__global__ __launch_bounds__(64) void attn_kernel(
    const float* __restrict__ q, const float* __restrict__ k, const float* __restrict__ v,
    const int* __restrict__ src, float* __restrict__ out, int heads, float scale)
{
    const int ch = CPL * 64;
    const int hc = heads * ch;
    int lane = threadIdx.x;
    int d = blockIdx.x;
    int h = blockIdx.y;
    const float* qp = q + (long)d * hc + h * ch;
    float qv[CPL];
    #pragma unroll
    for (int i = 0; i < CPL; i++) qv[i] = qp[i * 64 + lane];
    const int* sp = src + (long)d * FAN;
    int sidx[FAN];
    #pragma unroll
    for (int e = 0; e < FAN; e++) sidx[e] = sp[e];
    float logit[FAN];
    float mx = -1e30f;
    #pragma unroll
    for (int e = 0; e < FAN; e++) {
        const float* kp = k + (long)sidx[e] * hc + h * ch;
        float dot = 0.f;
        #pragma unroll
        for (int i = 0; i < CPL; i++) dot += qv[i] * kp[i * 64 + lane];
        #pragma unroll
        for (int off = 32; off > 0; off >>= 1) dot += __shfl_xor(dot, off, 64);
        dot *= scale;
        logit[e] = dot;
        mx = fmaxf(mx, dot);
    }
    float z = 0.f, p[FAN];
    #pragma unroll
    for (int e = 0; e < FAN; e++) { p[e] = __expf(logit[e] - mx); z += p[e]; }
    float inv = 1.0f / z;
    float acc[CPL] = {};
    #pragma unroll
    for (int e = 0; e < FAN; e++) {
        const float* vp = v + (long)sidx[e] * hc + h * ch;
        float w = p[e];
        #pragma unroll
        for (int i = 0; i < CPL; i++) acc[i] += w * vp[i * 64 + lane];
    }
    float* op = out + (long)d * hc + h * ch;
    #pragma unroll
    for (int i = 0; i < CPL; i++) op[i * 64 + lane] = acc[i] * inv;
}

// ---------------- Gated skip: g = sigmoid([o, xr, o-xr] @ Wb); y = g*xr+(1-g)*o ------
template<int CPL>   // hc/64
__global__ __launch_bounds__(64) void gate_kernel(
    const float* __restrict__ o, const float* __restrict__ xr,
    const float* __restrict__ Wb, float* __restrict__ y)
{
    const int hc = CPL * 64;
    int lane = threadIdx.x;
    long n = blockIdx.x;
    float ov[CPL], xv[CPL];
    float s = 0.f;
    #pragma unroll
    for (int i = 0; i < CPL; i++) {
        int c = i * 64 + lane;
        ov[i] = o[n * hc + c];
        xv[i] = xr[n * hc + c];
        s += ov[i] * Wb[c] + xv[i] * Wb[hc + c] + (ov[i] - xv[i]) * Wb[2 * hc + c];
    }
    #pragma unroll
    for (int off = 32; off > 0; off >>= 1) s += __shfl_xor(s, off, 64);
    float g = 1.0f / (1.0f + __expf(-s));
    #pragma unroll
    for (int i = 0; i < CPL; i++) {
        int c = i * 64 + lane;
        y[n * hc + c] = g * xv[i] + (1.0f - g) * ov[i];
    }
}

// ---------------- Column stats (mean/var over rows, per 256 features) ----------------
__global__ __launch_bounds__(256) void colstat_partial(
    const float* __restrict__ x, int M, float* __restrict__ ps, float* __restrict__ pss)
{
    int f = threadIdx.x;
    int b = blockIdx.x;   // 64 blocks
    float s = 0.f, ss = 0.f;
    for (int r = b; r < M; r += 64) {
        float v = x[(long)r * H + f];
        s += v; ss += v * v;
    }
    ps[b * H + f] = s;
    pss[b * H + f] = ss;
}

__global__ __launch_bounds__(256) void colstat_final(
    const float* __restrict__ ps, const float* __restrict__ pss, int M,
    float* __restrict__ mean, float* __restrict__ istd)
{
    int f = threadIdx.x;
    float s = 0.f, ss = 0.f;
    for (int b = 0; b < 64; b++) { s += ps[b * H + f]; ss += pss[b * H + f]; }
    float mu = s / M;
    float var = ss / M - mu * mu;
    mean[f] = mu;
    istd[f] = rsqrtf(var + 1e-5f);
}

__global__ __launch_bounds__(256) void norm_elu(
    float* __restrict__ x, const float* __restrict__ mean, const float* __restrict__ istd,
    int total)
{
    int i = blockIdx.x * 256 + threadIdx.x;
    if (i < total) {
        int f = i & (H - 1);
        float t = (x[i] - mean[f]) * istd[f];
        x[i] = t > 0.f ? t : __expf(t) - 1.0f;
    }
}

// ---------------- Semantic attention across the 3 relations ----------------
__global__ __launch_bounds__(256) void semantic_kernel(
    const float* __restrict__ emb,   // (3, N3, H)
    const float* __restrict__ Wo, const float* __restrict__ bo,
    const float* __restrict__ uo, const float* __restrict__ rl,
    float* __restrict__ outp)
{
    __shared__ float m_s[3][H];
    __shared__ float red[H];
    __shared__ float score_s[3];
    int n = blockIdx.x, c = threadIdx.x;
    for (int r = 0; r < 3; r++)
        m_s[r][c] = emb[((long)r * N3 + n) * H + c] * rl[r];
    __syncthreads();
    for (int r = 0; r < 3; r++) {
        float t = bo[c];
        for (int k2 = 0; k2 < H; k2++) t += m_s[r][k2] * Wo[k2 * H + c];
        red[c] = tanhf(t) * uo[c];
        __syncthreads();
        for (int s = 128; s > 0; s >>= 1) {
            if (c < s) red[c] += red[c + s];
            __syncthreads();
        }
        if (c == 0) score_s[r] = red[0];
        __syncthreads();
    }
    float s0 = score_s[0], s1 = score_s[1], s2 = score_s[2];
    float mx = fmaxf(s0, fmaxf(s1, s2));
    float e0 = __expf(s0 - mx), e1 = __expf(s1 - mx), e2 = __expf(s2 - mx);
    float zi = 1.0f / (e0 + e1 + e2);
    outp[(long)n * H + c] = (m_s[0][c] * e0 + m_s[1][c] * e1 + m_s[2][c] * e2) * zi;
}

static inline dim3 gemm_grid(int M, int N) {
    return dim3((M + 63) / 64, N / 64);
}

extern "C" void kernel_launch(void* const* d_in, const int* in_sizes, int n_in,
                              void* d_out, int out_size, void* d_ws, size_t ws_size,
                              hipStream_t stream) {
    const float* features = (const float*)d_in[0];
    const int*   n_ids    = (const int*)d_in[1];
    const int*   src1     = (const int*)d_in[2];
    const int*   src2     = (const int*)d_in[4];
    const int*   src3     = (const int*)d_in[6];
    // dict order: Wq, Wk, Wv, Ws, bq, bk, bv, bs, Wb
    const float* l1_Wq = (const float*)d_in[8];
    const float* l1_Wk = (const float*)d_in[9];
    const float* l1_Wv = (const float*)d_in[10];
    const float* l1_Ws = (const float*)d_in[11];
    const float* l1_bq = (const float*)d_in[12];
    const float* l1_bk = (const float*)d_in[13];
    const float* l1_bv = (const float*)d_in[14];
    const float* l1_bs = (const float*)d_in[15];
    const float* l1_Wb = (const float*)d_in[16];
    const float* l2_Wq = (const float*)d_in[17];
    const float* l2_Wk = (const float*)d_in[18];
    const float* l2_Wv = (const float*)d_in[19];
    const float* l2_Ws = (const float*)d_in[20];
    const float* l2_bq = (const float*)d_in[21];
    const float* l2_bk = (const float*)d_in[22];
    const float* l2_bv = (const float*)d_in[23];
    const float* l2_bs = (const float*)d_in[24];
    const float* l2_Wb = (const float*)d_in[25];
    const float* l3_Wq = (const float*)d_in[26];
    const float* l3_Wk = (const float*)d_in[27];
    const float* l3_Wv = (const float*)d_in[28];
    const float* l3_Ws = (const float*)d_in[29];
    const float* l3_bq = (const float*)d_in[30];
    const float* l3_bk = (const float*)d_in[31];
    const float* l3_bv = (const float*)d_in[32];
    const float* l3_bs = (const float*)d_in[33];
    const float* l3_Wb = (const float*)d_in[34];
    const float* w_omega = (const float*)d_in[35];
    const float* b_omega = (const float*)d_in[36];
    const float* u_omega = (const float*)d_in[37];
    const float* rl      = (const float*)d_in[38];

    float* ws = (float*)d_ws;
    size_t off = 0;
    float* emb  = ws + off; off += (size_t)3 * N3 * H;       // persistent across relations
    float* q1   = ws + off; off += (size_t)N1 * H;
    float* s1   = ws + off; off += (size_t)N1 * H;
    float* o1   = ws + off; off += (size_t)N1 * H;
    float* x1   = ws + off; off += (size_t)N1 * H;
    float* ps   = ws + off; off += 64 * H;
    float* pss  = ws + off; off += 64 * H;
    float* mean_= ws + off; off += H;
    float* istd = ws + off; off += H;
    float* k1   = ws + off; off += (size_t)N0 * H;           // 12.8M floats
    float* v1   = ws + off; off += (size_t)N0 * H;           // 12.8M floats
    // L2 buffers alias the (dead-after-L1-attention) k1 region
    float* k2 = k1;                     // N1 x 128
    float* v2 = k2 + (size_t)N1 * 128;
    float* q2 = v2 + (size_t)N1 * 128;  // N2 x 128
    float* s2 = q2 + (size_t)N2 * 128;
    float* o2 = s2 + (size_t)N2 * 128;
    float* x2 = o2 + (size_t)N2 * 128;
    // L3 buffers alias the v1 region
    float* k3 = v1;                     // N2 x 256
    float* v3 = k3 + (size_t)N2 * H;
    float* q3 = v3 + (size_t)N2 * H;    // N3 x 256
    float* s3 = q3 + (size_t)N3 * H;
    float* o3 = s3 + (size_t)N3 * H;

    const float sc128 = 0.088388347648318447f;  // 1/sqrt(128)
    const float sc256 = 0.0625f;                // 1/sqrt(256)

    for (int r = 0; r < 3; r++) {
        const int* idx = n_ids + (size_t)r * N0;
        // ---- Layer 1 (din=256, heads=2, ch=128, hc=256) ----
        gemm_bias<<<gemm_grid(N0, H), 256, 0, stream>>>(
            features, idx, l1_Wk + (size_t)r * H * H, l1_bk + (size_t)r * H, k1, N0, H, H);
        gemm_bias<<<gemm_grid(N0, H), 256, 0, stream>>>(
            features, idx, l1_Wv + (size_t)r * H * H, l1_bv + (size_t)r * H, v1, N0, H, H);
        gemm_bias<<<gemm_grid(N1, H), 256, 0, stream>>>(
            features, idx, l1_Wq + (size_t)r * H * H, l1_bq + (size_t)r * H, q1, N1, H, H);
        gemm_bias<<<gemm_grid(N1, H), 256, 0, stream>>>(
            features, idx, l1_Ws + (size_t)r * H * H, l1_bs + (size_t)r * H, s1, N1, H, H);
        attn_kernel<2><<<dim3(N1, 2), 64, 0, stream>>>(
            q1, k1, v1, src1 + (size_t)r * N1 * FAN, o1, 2, sc128);
        gate_kernel<4><<<N1, 64, 0, stream>>>(o1, s1, l1_Wb + (size_t)r * 3 * H, x1);
        // ---- col-norm + ELU ----
        colstat_partial<<<64, 256, 0, stream>>>(x1, N1, ps, pss);
        colstat_final<<<1, 256, 0, stream>>>(ps, pss, N1, mean_, istd);
        norm_elu<<<(N1 * H + 255) / 256, 256, 0, stream>>>(x1, mean_, istd, N1 * H);
        // ---- Layer 2 (din=256, heads=1, ch=128, hc=128) ----
        gemm_bias<<<gemm_grid(N1, 128), 256, 0, stream>>>(
            x1, nullptr, l2_Wk + (size_t)r * H * 128, l2_bk + (size_t)r * 128, k2, N1, H, 128);
        gemm_bias<<<gemm_grid(N1, 128), 256, 0, stream>>>(
            x1, nullptr, l2_Wv + (size_t)r * H * 128, l2_bv + (size_t)r * 128, v2, N1, H, 128);
        gemm_bias<<<gemm_grid(N2, 128), 256, 0, stream>>>(
            x1, nullptr, l2_Wq + (size_t)r * H * 128, l2_bq + (size_t)r * 128, q2, N2, H, 128);
        gemm_bias<<<gemm_grid(N2, 128), 256, 0, stream>>>(
            x1, nullptr, l2_Ws + (size_t)r * H * 128, l2_bs + (size_t)r * 128, s2, N2, H, 128);
        attn_kernel<2><<<dim3(N2, 1), 64, 0, stream>>>(
            q2, k2, v2, src2 + (size_t)r * N2 * FAN, o2, 1, sc128);
        gate_kernel<2><<<N2, 64, 0, stream>>>(o2, s2, l2_Wb + (size_t)r * 384, x2);
        // ---- Layer 3 (din=128, heads=1, ch=256, hc=256) ----
        gemm_bias<<<gemm_grid(N2, H), 256, 0, stream>>>(
            x2, nullptr, l3_Wk + (size_t)r * 128 * H, l3_bk + (size_t)r * H, k3, N2, 128, H);
        gemm_bias<<<gemm_grid(N2, H), 256, 0, stream>>>(
            x2, nullptr, l3_Wv + (size_t)r * 128 * H, l3_bv + (size_t)r * H, v3, N2, 128, H);
        gemm_bias<<<gemm_grid(N3, H), 256, 0, stream>>>(
            x2, nullptr, l3_Wq + (size_t)r * 128 * H, l3_bq + (size_t)r * H, q3, N3, 128, H);
        gemm_bias<<<gemm_grid(N3, H), 256, 0, stream>>>(
            x2, nullptr, l3_Ws + (size_t)r * 128 * H, l3_bs + (size_t)r * H, s3, N3, 128, H);
        attn_kernel<4><<<dim3(N3, 1), 64, 0, stream>>>(
            q3, k3, v3, src3 + (size_t)r * N3 * FAN, o3, 1, sc256);
        gate_kernel<4><<<N3, 64, 0, stream>>>(
            o3, s3, l3_Wb + (size_t)r * 3 * H, emb + (size_t)r * N3 * H);
    }
    semantic_kernel<<<N3, 256, 0, stream>>>(emb, w_omega, b_omega, u_omega, rl, (float*)d_out);
}

// Round 2
// 1063.712 us; speedup vs baseline: 2.4368x; 2.4368x over previous
//
#include <hip/hip_runtime.h>
#include <hip/hip_bf16.h>
#include <math.h>

#define H 256
#define N0 50000
#define N1 10000
#define N2 4000
#define N3 1024
#define FAN 16

typedef __hip_bfloat16 bf16;
typedef __attribute__((ext_vector_type(8))) short short8;
typedef __attribute__((ext_vector_type(4))) float floatx4;

typedef const __attribute__((address_space(1))) void* gas_ptr;
typedef __attribute__((address_space(3))) void* las_ptr;

__device__ __forceinline__ void load_lds16(const void* g, void* l) {
    __builtin_amdgcn_global_load_lds((gas_ptr)g, (las_ptr)l, 16, 0, 0);
}

// ---------------- bf16 MFMA GEMM: C[m,n] = bias[n] + sum_k A[m,k] * Bt[n,k] ----------
// A: M x K bf16 row-major.  Bt: N x K bf16 row-major (pre-transposed weights).
// 128x128 tile, 256 threads (4 waves, each a 64x64 subtile of 4x4 16x16x32 mfma).
// Staging via global_load_lds width=16; XOR chunk swizzle on the GLOBAL address side
// (LDS side must be lane-contiguous) turns the 8-way frag-read conflict into 2-way.
template<typename OutT>
__global__ __launch_bounds__(256) void gemm_mfma(
    const bf16* __restrict__ A, const bf16* __restrict__ Bt,
    const float* __restrict__ b1, const float* __restrict__ b2, int Nh,
    OutT* __restrict__ C, int M, int K, int N)
{
    __shared__ bf16 A_s[128 * 32];
    __shared__ bf16 B_s[128 * 32];
    const int tid = threadIdx.x;
    const int lane = tid & 63;
    const int w = tid >> 6;
    const int m0 = blockIdx.x * 128;
    const int n0 = blockIdx.y * 128;
    const int wr = (w >> 1) * 64;
    const int wc = (w & 1) * 64;
    const int q = lane >> 4;
    const int lm = lane & 15;
    const int srow = lane >> 2;   // row within a 16-row staging issue
    const int slot = lane & 3;    // 16B chunk slot within a 64B row

    floatx4 acc[4][4];
    #pragma unroll
    for (int i = 0; i < 4; i++)
        #pragma unroll
        for (int j = 0; j < 4; j++)
            acc[i][j] = (floatx4){0.f, 0.f, 0.f, 0.f};

    for (int k0 = 0; k0 < K; k0 += 32) {
        #pragma unroll
        for (int t = 0; t < 2; t++) {
            int rA = t * 64 + w * 16 + srow;                    // tile row 0..127
            int cA = slot ^ ((rA >> 1) & 3);                    // swizzled k-chunk
            int gr = m0 + rA; gr = gr < M ? gr : M - 1;         // clamp (stores guarded)
            load_lds16(A + (size_t)gr * K + k0 + cA * 8,
                       A_s + (size_t)(t * 64 + w * 16) * 32);
            int rB = t * 64 + w * 16 + srow;                    // tile col 0..127
            int cB = slot ^ ((rB >> 1) & 3);
            load_lds16(Bt + (size_t)(n0 + rB) * K + k0 + cB * 8,
                       B_s + (size_t)(t * 64 + w * 16) * 32);
        }
        __syncthreads();
        short8 af[4], bfr[4];
        #pragma unroll
        for (int mi = 0; mi < 4; mi++) {
            int row = wr + mi * 16 + lm;
            af[mi] = *(const short8*)(A_s + row * 32 + (q ^ ((row >> 1) & 3)) * 8);
        }
        #pragma unroll
        for (int ni = 0; ni < 4; ni++) {
            int col = wc + ni * 16 + lm;
            bfr[ni] = *(const short8*)(B_s + col * 32 + (q ^ ((col >> 1) & 3)) * 8);
        }
        #pragma unroll
        for (int mi = 0; mi < 4; mi++)
            #pragma unroll
            for (int ni = 0; ni < 4; ni++)
                acc[mi][ni] = __builtin_amdgcn_mfma_f32_16x16x32_bf16(
                    af[mi], bfr[ni], acc[mi][ni], 0, 0, 0);
        __syncthreads();
    }
    // C/D layout: col = lane&15, row = (lane>>4)*4 + reg  [m89]
    #pragma unroll
    for (int ni = 0; ni < 4; ni++) {
        int col = n0 + wc + ni * 16 + lm;
        float bias = (col < Nh) ? b1[col] : b2[col - Nh];
        #pragma unroll
        for (int mi = 0; mi < 4; mi++) {
            int rb = m0 + wr + mi * 16 + q * 4;
            #pragma unroll
            for (int rg = 0; rg < 4; rg++) {
                int rr = rb + rg;
                if (rr < M) C[(size_t)rr * N + col] = (OutT)(acc[mi][ni][rg] + bias);
            }
        }
    }
}

// ---------------- gather rows of features -> bf16 ----------------
__global__ __launch_bounds__(256) void gather_bf16(
    const float* __restrict__ F, const int* __restrict__ idx, bf16* __restrict__ out)
{
    int row = blockIdx.x, c = threadIdx.x;
    out[(size_t)row * H + c] = (bf16)F[(size_t)idx[row] * H + c];
}

// ---------------- weight pack: Wt[n][k] = {W1|W2}[k][n], bf16 ----------------
__global__ void pack_bt(const float* __restrict__ W1, const float* __restrict__ W2,
                        bf16* __restrict__ Wt, int K, int Nh)
{
    int nn = blockIdx.x;   // 0..2*Nh-1
    int k = threadIdx.x;   // K threads
    float v = (nn < Nh) ? W1[(size_t)k * Nh + nn] : W2[(size_t)k * Nh + (nn - Nh)];
    Wt[(size_t)nn * K + k] = (bf16)v;
}

// ---------------- attention: one wave per (dst,head); k/v bf16, strided in kv ------
template<int CPL, int HEADS>   // ch = CPL*64
__global__ __launch_bounds__(256) void attn_kernel(
    const float* __restrict__ qbuf, int qN,
    const bf16* __restrict__ kv, int kvN, int vOff,
    const int* __restrict__ src, float* __restrict__ out,
    int ndst, float scale)
{
    const int ch = CPL * 64;
    const int hc = HEADS * ch;
    int lane = threadIdx.x & 63;
    int wid = blockIdx.x * 4 + (threadIdx.x >> 6);
    if (wid >= ndst * HEADS) return;
    int d = wid / HEADS;
    int h = wid - d * HEADS;
    const float* qp = qbuf + (size_t)d * qN + h * ch;
    float qv[CPL];
    #pragma unroll
    for (int i = 0; i < CPL; i++) qv[i] = qp[i * 64 + lane];
    const int* sp = src + (size_t)d * FAN;
    int sidx[FAN];
    #pragma unroll
    for (int e = 0; e < FAN; e++) sidx[e] = sp[e];
    float logit[FAN], mx = -1e30f;
    #pragma unroll
    for (int e = 0; e < FAN; e++) {
        const bf16* kp = kv + (size_t)sidx[e] * kvN + h * ch;
        float dot = 0.f;
        #pragma unroll
        for (int i = 0; i < CPL; i++) dot += qv[i] * (float)kp[i * 64 + lane];
        #pragma unroll
        for (int off = 32; off > 0; off >>= 1) dot += __shfl_xor(dot, off, 64);
        dot *= scale;
        logit[e] = dot;
        mx = fmaxf(mx, dot);
    }
    float z = 0.f, p[FAN];
    #pragma unroll
    for (int e = 0; e < FAN; e++) { p[e] = __expf(logit[e] - mx); z += p[e]; }
    float inv = 1.f / z;
    float accv[CPL] = {};
    #pragma unroll
    for (int e = 0; e < FAN; e++) {
        const bf16* vp = kv + (size_t)sidx[e] * kvN + vOff + h * ch;
        #pragma unroll
        for (int i = 0; i < CPL; i++) accv[i] += p[e] * (float)vp[i * 64 + lane];
    }
    float* op = out + (size_t)d * hc + h * ch;
    #pragma unroll
    for (int i = 0; i < CPL; i++) op[i * 64 + lane] = accv[i] * inv;
}

// ---------------- gated skip; optional fp32 / bf16 outputs ----------------
template<int CPL>   // hc = CPL*64
__global__ __launch_bounds__(256) void gate_kernel(
    const float* __restrict__ o,
    const float* __restrict__ xr, int xrN, int xrOff,
    const float* __restrict__ Wb,
    float* __restrict__ yf, bf16* __restrict__ yb, int n)
{
    const int hc = CPL * 64;
    int lane = threadIdx.x & 63;
    int row = blockIdx.x * 4 + (threadIdx.x >> 6);
    if (row >= n) return;
    const float* op = o + (size_t)row * hc;
    const float* xp = xr + (size_t)row * xrN + xrOff;
    float ov[CPL], xv[CPL], s = 0.f;
    #pragma unroll
    for (int i = 0; i < CPL; i++) {
        int c = i * 64 + lane;
        ov[i] = op[c];
        xv[i] = xp[c];
        s += ov[i] * Wb[c] + xv[i] * Wb[hc + c] + (ov[i] - xv[i]) * Wb[2 * hc + c];
    }
    #pragma unroll
    for (int off = 32; off > 0; off >>= 1) s += __shfl_xor(s, off, 64);
    float g = 1.f / (1.f + __expf(-s));
    #pragma unroll
    for (int i = 0; i < CPL; i++) {
        int c = i * 64 + lane;
        float yv = g * xv[i] + (1.f - g) * ov[i];
        if (yf) yf[(size_t)row * hc + c] = yv;
        if (yb) yb[(size_t)row * hc + c] = (bf16)yv;
    }
}

// ---------------- column stats + norm+ELU (bf16 out) ----------------
__global__ __launch_bounds__(256) void colstat_partial(
    const float* __restrict__ x, int M, float* __restrict__ ps, float* __restrict__ pss)
{
    int f = threadIdx.x;
    int b = blockIdx.x;   // 64 blocks
    float s = 0.f, ss = 0.f;
    for (int r = b; r < M; r += 64) {
        float v = x[(size_t)r * H + f];
        s += v; ss += v * v;
    }
    ps[b * H + f] = s;
    pss[b * H + f] = ss;
}

__global__ __launch_bounds__(256) void colstat_final(
    const float* __restrict__ ps, const float* __restrict__ pss, int M,
    float* __restrict__ mean, float* __restrict__ istd)
{
    int f = threadIdx.x;
    float s = 0.f, ss = 0.f;
    for (int b = 0; b < 64; b++) { s += ps[b * H + f]; ss += pss[b * H + f]; }
    float mu = s / M;
    float var = ss / M - mu * mu;
    mean[f] = mu;
    istd[f] = rsqrtf(var + 1e-5f);
}

__global__ __launch_bounds__(256) void norm_elu_bf16(
    const float* __restrict__ x, const float* __restrict__ mean,
    const float* __restrict__ istd, bf16* __restrict__ out, int total)
{
    int i = blockIdx.x * 256 + threadIdx.x;
    if (i < total) {
        int f = i & (H - 1);
        float t = (x[i] - mean[f]) * istd[f];
        out[i] = (bf16)(t > 0.f ? t : __expf(t) - 1.0f);
    }
}

// ---------------- semantic attention across the 3 relations ----------------
__global__ __launch_bounds__(256) void semantic_kernel(
    const float* __restrict__ emb,   // (3, N3, H)
    const float* __restrict__ Wo, const float* __restrict__ bo,
    const float* __restrict__ uo, const float* __restrict__ rl,
    float* __restrict__ outp)
{
    __shared__ float m_s[3][H];
    __shared__ float red[H];
    __shared__ float score_s[3];
    int n = blockIdx.x, c = threadIdx.x;
    for (int r = 0; r < 3; r++)
        m_s[r][c] = emb[((size_t)r * N3 + n) * H + c] * rl[r];
    __syncthreads();
    for (int r = 0; r < 3; r++) {
        float t = bo[c];
        for (int k2 = 0; k2 < H; k2++) t += m_s[r][k2] * Wo[k2 * H + c];
        red[c] = tanhf(t) * uo[c];
        __syncthreads();
        for (int s = 128; s > 0; s >>= 1) {
            if (c < s) red[c] += red[c + s];
            __syncthreads();
        }
        if (c == 0) score_s[r] = red[0];
        __syncthreads();
    }
    float s0 = score_s[0], s1 = score_s[1], s2 = score_s[2];
    float mx = fmaxf(s0, fmaxf(s1, s2));
    float e0 = __expf(s0 - mx), e1 = __expf(s1 - mx), e2 = __expf(s2 - mx);
    float zi = 1.0f / (e0 + e1 + e2);
    outp[(size_t)n * H + c] = (m_s[0][c] * e0 + m_s[1][c] * e1 + m_s[2][c] * e2) * zi;
}

extern "C" void kernel_launch(void* const* d_in, const int* in_sizes, int n_in,
                              void* d_out, int out_size, void* d_ws, size_t ws_size,
                              hipStream_t stream) {
    const float* features = (const float*)d_in[0];
    const int*   n_ids    = (const int*)d_in[1];
    const int*   src1     = (const int*)d_in[2];
    const int*   src2     = (const int*)d_in[4];
    const int*   src3     = (const int*)d_in[6];
    // dict order per layer: Wq, Wk, Wv, Ws, bq, bk, bv, bs, Wb
    const float* l1_Wq = (const float*)d_in[8];
    const float* l1_Wk = (const float*)d_in[9];
    const float* l1_Wv = (const float*)d_in[10];
    const float* l1_Ws = (const float*)d_in[11];
    const float* l1_bq = (const float*)d_in[12];
    const float* l1_bk = (const float*)d_in[13];
    const float* l1_bv = (const float*)d_in[14];
    const float* l1_bs = (const float*)d_in[15];
    const float* l1_Wb = (const float*)d_in[16];
    const float* l2_Wq = (const float*)d_in[17];
    const float* l2_Wk = (const float*)d_in[18];
    const float* l2_Wv = (const float*)d_in[19];
    const float* l2_Ws = (const float*)d_in[20];
    const float* l2_bq = (const float*)d_in[21];
    const float* l2_bk = (const float*)d_in[22];
    const float* l2_bv = (const float*)d_in[23];
    const float* l2_bs = (const float*)d_in[24];
    const float* l2_Wb = (const float*)d_in[25];
    const float* l3_Wq = (const float*)d_in[26];
    const float* l3_Wk = (const float*)d_in[27];
    const float* l3_Wv = (const float*)d_in[28];
    const float* l3_Ws = (const float*)d_in[29];
    const float* l3_bq = (const float*)d_in[30];
    const float* l3_bk = (const float*)d_in[31];
    const float* l3_bv = (const float*)d_in[32];
    const float* l3_bs = (const float*)d_in[33];
    const float* l3_Wb = (const float*)d_in[34];
    const float* w_omega = (const float*)d_in[35];
    const float* b_omega = (const float*)d_in[36];
    const float* u_omega = (const float*)d_in[37];
    const float* rl      = (const float*)d_in[38];

    // ---- workspace layout (~124 MB) ----
    float* ws = (float*)d_ws;
    size_t o = 0;
    float* emb = ws + o; o += (size_t)3 * N3 * H;
    float* qs1 = ws + o; o += (size_t)N1 * 512;   // also reused as qs2 / qs3
    float* o1  = ws + o; o += (size_t)N1 * 256;   // also reused as o2 / o3
    float* x1  = ws + o; o += (size_t)N1 * 256;
    float* ps  = ws + o; o += 64 * H;
    float* pss = ws + o; o += 64 * H;
    float* mean_ = ws + o; o += H;
    float* istd  = ws + o; o += H;
    float* qs2 = qs1; float* qs3 = qs1;
    float* o2  = o1;  float* o3  = o1;

    bf16* bws = (bf16*)(ws + o);
    size_t b = 0;
    bf16* Xg  = bws + b; b += (size_t)N0 * H;
    bf16* kv1 = bws + b; b += (size_t)N0 * 512;
    // sub-aliases inside kv1 (kv1 dead after L1 attention):
    bf16* x1b = kv1;
    bf16* kv2 = x1b + (size_t)N1 * 256;
    bf16* x2b = kv2 + (size_t)N1 * 256;
    bf16* kv3 = x2b + (size_t)N2 * 128;
    // packed transposed bf16 weights, 3 relations each
    bf16* Wkv1 = bws + b; b += (size_t)3 * 512 * H;
    bf16* Wqs1 = bws + b; b += (size_t)3 * 512 * H;
    bf16* Wkv2 = bws + b; b += (size_t)3 * 256 * H;
    bf16* Wqs2 = bws + b; b += (size_t)3 * 256 * H;
    bf16* Wkv3 = bws + b; b += (size_t)3 * 512 * 128;
    bf16* Wqs3 = bws + b; b += (size_t)3 * 512 * 128;

    const float sc128 = 0.088388347648318447f;  // 1/sqrt(128)
    const float sc256 = 0.0625f;                // 1/sqrt(256)

    // ---- pack all weights (tiny) ----
    for (int r = 0; r < 3; r++) {
        pack_bt<<<512, 256, 0, stream>>>(l1_Wk + (size_t)r * H * H, l1_Wv + (size_t)r * H * H,
                                         Wkv1 + (size_t)r * 512 * H, 256, 256);
        pack_bt<<<512, 256, 0, stream>>>(l1_Wq + (size_t)r * H * H, l1_Ws + (size_t)r * H * H,
                                         Wqs1 + (size_t)r * 512 * H, 256, 256);
        pack_bt<<<256, 256, 0, stream>>>(l2_Wk + (size_t)r * H * 128, l2_Wv + (size_t)r * H * 128,
                                         Wkv2 + (size_t)r * 256 * H, 256, 128);
        pack_bt<<<256, 256, 0, stream>>>(l2_Wq + (size_t)r * H * 128, l2_Ws + (size_t)r * H * 128,
                                         Wqs2 + (size_t)r * 256 * H, 256, 128);
        pack_bt<<<512, 128, 0, stream>>>(l3_Wk + (size_t)r * 128 * H, l3_Wv + (size_t)r * 128 * H,
                                         Wkv3 + (size_t)r * 512 * 128, 128, 256);
        pack_bt<<<512, 128, 0, stream>>>(l3_Wq + (size_t)r * 128 * H, l3_Ws + (size_t)r * 128 * H,
                                         Wqs3 + (size_t)r * 512 * 128, 128, 256);
    }

    for (int r = 0; r < 3; r++) {
        gather_bf16<<<N0, 256, 0, stream>>>(features, n_ids + (size_t)r * N0, Xg);
        // ---- L1: din=256, heads=2, ch=128, hc=256 ----
        gemm_mfma<bf16><<<dim3((N0 + 127) / 128, 4), 256, 0, stream>>>(
            Xg, Wkv1 + (size_t)r * 512 * H, l1_bk + (size_t)r * H, l1_bv + (size_t)r * H, 256,
            kv1, N0, 256, 512);
        gemm_mfma<float><<<dim3((N1 + 127) / 128, 4), 256, 0, stream>>>(
            Xg, Wqs1 + (size_t)r * 512 * H, l1_bq + (size_t)r * H, l1_bs + (size_t)r * H, 256,
            qs1, N1, 256, 512);
        attn_kernel<2, 2><<<(N1 * 2 + 3) / 4, 256, 0, stream>>>(
            qs1, 512, kv1, 512, 256, src1 + (size_t)r * N1 * FAN, o1, N1, sc128);
        gate_kernel<4><<<(N1 + 3) / 4, 256, 0, stream>>>(
            o1, qs1, 512, 256, l1_Wb + (size_t)r * 3 * H, x1, (bf16*)nullptr, N1);
        colstat_partial<<<64, 256, 0, stream>>>(x1, N1, ps, pss);
        colstat_final<<<1, 256, 0, stream>>>(ps, pss, N1, mean_, istd);
        norm_elu_bf16<<<(N1 * H + 255) / 256, 256, 0, stream>>>(x1, mean_, istd, x1b, N1 * H);
        // ---- L2: din=256, heads=1, ch=128, hc=128 ----
        gemm_mfma<bf16><<<dim3((N1 + 127) / 128, 2), 256, 0, stream>>>(
            x1b, Wkv2 + (size_t)r * 256 * H, l2_bk + (size_t)r * 128, l2_bv + (size_t)r * 128, 128,
            kv2, N1, 256, 256);
        gemm_mfma<float><<<dim3((N2 + 127) / 128, 2), 256, 0, stream>>>(
            x1b, Wqs2 + (size_t)r * 256 * H, l2_bq + (size_t)r * 128, l2_bs + (size_t)r * 128, 128,
            qs2, N2, 256, 256);
        attn_kernel<2, 1><<<(N2 + 3) / 4, 256, 0, stream>>>(
            qs2, 256, kv2, 256, 128, src2 + (size_t)r * N2 * FAN, o2, N2, sc128);
        gate_kernel<2><<<(N2 + 3) / 4, 256, 0, stream>>>(
            o2, qs2, 256, 128, l2_Wb + (size_t)r * 384, (float*)nullptr, x2b, N2);
        // ---- L3: din=128, heads=1, ch=256, hc=256 ----
        gemm_mfma<bf16><<<dim3((N2 + 127) / 128, 4), 256, 0, stream>>>(
            x2b, Wkv3 + (size_t)r * 512 * 128, l3_bk + (size_t)r * H, l3_bv + (size_t)r * H, 256,
            kv3, N2, 128, 512);
        gemm_mfma<float><<<dim3((N3 + 127) / 128, 4), 256, 0, stream>>>(
            x2b, Wqs3 + (size_t)r * 512 * 128, l3_bq + (size_t)r * H, l3_bs + (size_t)r * H, 256,
            qs3, N3, 128, 512);
        attn_kernel<4, 1><<<(N3 + 3) / 4, 256, 0, stream>>>(
            qs3, 512, kv3, 512, 256, src3 + (size_t)r * N3 * FAN, o3, N3, sc256);
        gate_kernel<4><<<(N3 + 3) / 4, 256, 0, stream>>>(
            o3, qs3, 512, 256, l3_Wb + (size_t)r * 3 * H, emb + (size_t)r * N3 * H,
            (bf16*)nullptr, N3);
    }
    semantic_kernel<<<N3, 256, 0, stream>>>(emb, w_omega, b_omega, u_omega, rl, (float*)d_out);
}

// Round 3
// 1006.379 us; speedup vs baseline: 2.5757x; 1.0570x over previous
//
#include <hip/hip_runtime.h>
#include <hip/hip_bf16.h>
#include <math.h>

#define H 256
#define N0 50000
#define N1 10000
#define N2 4000
#define N3 1024
#define FAN 16

typedef __hip_bfloat16 bf16;
typedef __attribute__((ext_vector_type(8))) short short8;
typedef __attribute__((ext_vector_type(4))) short short4v;
typedef __attribute__((ext_vector_type(4))) float floatx4;

// ---------------- register-resident MFMA GEMM, no main-loop LDS/barriers ----------
// C[m,n] = bias[n] + sum_k A[m,k] * Bt[n,k]
// A: M x K bf16 row-major. Bt: N x K bf16 row-major. K compile-time (128/256).
// Block = 256 threads = 4 waves; wave w computes rows [bx*256+w*64, +64) x cols
// [by*64, +64) as 4x4 mfma_f32_16x16x32_bf16 tiles. A/B frags loaded straight
// from global (16 full 64B lines per frag-load wave-wide); B is L2-resident.
// bf16 output goes through an LDS transpose so global stores are 128B-contiguous.
template<typename OutT, int K>
__global__ __launch_bounds__(256, 2) void gemm_rr(
    const bf16* __restrict__ A, const bf16* __restrict__ Bt,
    const float* __restrict__ b1, const float* __restrict__ b2, int Nh,
    OutT* __restrict__ C, int M, int N)
{
    constexpr bool BF16OUT = (sizeof(OutT) == 2);
    constexpr int PITCH = 72;                       // bf16 elems; 144B rows, 16B-aligned
    __shared__ bf16 stg[BF16OUT ? 4 * 64 * PITCH : 8];

    const int lane = threadIdx.x & 63;
    const int w = threadIdx.x >> 6;
    const int lm = lane & 15;
    const int q = lane >> 4;
    const int mbase = blockIdx.x * 256 + w * 64;
    const int n0 = blockIdx.y * 64;

    // per-fragment row/col base pointers (k-invariant)
    const bf16* arow[4];
    const bf16* brow[4];
    #pragma unroll
    for (int i = 0; i < 4; i++) {
        int r = mbase + i * 16 + lm;
        r = r < M ? r : M - 1;                      // clamp; stores are guarded
        arow[i] = A + (size_t)r * K + q * 8;
        brow[i] = Bt + (size_t)(n0 + i * 16 + lm) * K + q * 8;
    }

    floatx4 acc[4][4];
    #pragma unroll
    for (int i = 0; i < 4; i++)
        #pragma unroll
        for (int j = 0; j < 4; j++)
            acc[i][j] = (floatx4){0.f, 0.f, 0.f, 0.f};

    #pragma unroll
    for (int kc = 0; kc < K / 32; kc++) {
        short8 a[4], bb[4];
        #pragma unroll
        for (int i = 0; i < 4; i++) a[i] = *(const short8*)(arow[i] + kc * 32);
        #pragma unroll
        for (int j = 0; j < 4; j++) bb[j] = *(const short8*)(brow[j] + kc * 32);
        #pragma unroll
        for (int i = 0; i < 4; i++)
            #pragma unroll
            for (int j = 0; j < 4; j++)
                acc[i][j] = __builtin_amdgcn_mfma_f32_16x16x32_bf16(
                    a[i], bb[j], acc[i][j], 0, 0, 0);
    }

    // C/D layout: col = lane&15, row = (lane>>4)*4 + reg  [m89]
    if constexpr (BF16OUT) {
        bf16* s = stg + w * 64 * PITCH;
        #pragma unroll
        for (int ni = 0; ni < 4; ni++) {
            int colg = n0 + ni * 16 + lm;
            float bias = (colg < Nh) ? b1[colg] : b2[colg - Nh];
            #pragma unroll
            for (int mi = 0; mi < 4; mi++)
                #pragma unroll
                for (int rg = 0; rg < 4; rg++) {
                    int row = mi * 16 + q * 4 + rg;
                    s[row * PITCH + ni * 16 + lm] = (bf16)(acc[mi][ni][rg] + bias);
                }
        }
        __syncthreads();
        #pragma unroll
        for (int it = 0; it < 8; it++) {
            int row = it * 8 + (lane >> 3);
            int grow = mbase + row;
            short8 vv = *(const short8*)(s + row * PITCH + (lane & 7) * 8);
            if (grow < M)
                *(short8*)(C + (size_t)grow * N + n0 + (lane & 7) * 8) = vv;
        }
    } else {
        #pragma unroll
        for (int ni = 0; ni < 4; ni++) {
            int colg = n0 + ni * 16 + lm;
            float bias = (colg < Nh) ? b1[colg] : b2[colg - Nh];
            #pragma unroll
            for (int mi = 0; mi < 4; mi++) {
                int rb = mbase + mi * 16 + q * 4;
                #pragma unroll
                for (int rg = 0; rg < 4; rg++) {
                    int rr = rb + rg;
                    if (rr < M) C[(size_t)rr * N + colg] = acc[mi][ni][rg] + bias;
                }
            }
        }
    }
}

// ---------------- gather rows of features -> bf16 (float4 in, 8B out) ----------------
__global__ __launch_bounds__(256) void gather_bf16(
    const float* __restrict__ F, const int* __restrict__ idx, bf16* __restrict__ out,
    int nrows)
{
    int t = blockIdx.x * 256 + threadIdx.x;
    int row = t >> 6;                 // wave-uniform
    if (row >= nrows) return;
    int c4 = (t & 63) * 4;
    float4 v = *(const float4*)(F + (size_t)idx[row] * H + c4);
    bf16 tmp[4] = {(bf16)v.x, (bf16)v.y, (bf16)v.z, (bf16)v.w};
    *(short4v*)(out + (size_t)row * H + c4) = *(const short4v*)tmp;
}

// ---------------- weight pack: Wt[n][k] = {W1|W2}[k][n], bf16 ----------------
__global__ void pack_bt(const float* __restrict__ W1, const float* __restrict__ W2,
                        bf16* __restrict__ Wt, int K, int Nh)
{
    int nn = blockIdx.x;   // 0..2*Nh-1
    int k = threadIdx.x;   // K threads
    float v = (nn < Nh) ? W1[(size_t)k * Nh + nn] : W2[(size_t)k * Nh + (nn - Nh)];
    Wt[(size_t)nn * K + k] = (bf16)v;
}

// ---------------- attention: one wave per (dst,head); k/v bf16, strided in kv ------
template<int CPL, int HEADS>   // ch = CPL*64
__global__ __launch_bounds__(256) void attn_kernel(
    const float* __restrict__ qbuf, int qN,
    const bf16* __restrict__ kv, int kvN, int vOff,
    const int* __restrict__ src, float* __restrict__ out,
    int ndst, float scale)
{
    const int ch = CPL * 64;
    const int hc = HEADS * ch;
    int lane = threadIdx.x & 63;
    int wid = blockIdx.x * 4 + (threadIdx.x >> 6);
    if (wid >= ndst * HEADS) return;
    int d = wid / HEADS;
    int h = wid - d * HEADS;
    const float* qp = qbuf + (size_t)d * qN + h * ch;
    float qv[CPL];
    #pragma unroll
    for (int i = 0; i < CPL; i++) qv[i] = qp[i * 64 + lane];
    const int* sp = src + (size_t)d * FAN;
    int sidx[FAN];
    #pragma unroll
    for (int e = 0; e < FAN; e++) sidx[e] = sp[e];
    float logit[FAN], mx = -1e30f;
    #pragma unroll
    for (int e = 0; e < FAN; e++) {
        const bf16* kp = kv + (size_t)sidx[e] * kvN + h * ch;
        float dot = 0.f;
        #pragma unroll
        for (int i = 0; i < CPL; i++) dot += qv[i] * (float)kp[i * 64 + lane];
        #pragma unroll
        for (int off = 32; off > 0; off >>= 1) dot += __shfl_xor(dot, off, 64);
        dot *= scale;
        logit[e] = dot;
        mx = fmaxf(mx, dot);
    }
    float z = 0.f, p[FAN];
    #pragma unroll
    for (int e = 0; e < FAN; e++) { p[e] = __expf(logit[e] - mx); z += p[e]; }
    float inv = 1.f / z;
    float accv[CPL] = {};
    #pragma unroll
    for (int e = 0; e < FAN; e++) {
        const bf16* vp = kv + (size_t)sidx[e] * kvN + vOff + h * ch;
        #pragma unroll
        for (int i = 0; i < CPL; i++) accv[i] += p[e] * (float)vp[i * 64 + lane];
    }
    float* op = out + (size_t)d * hc + h * ch;
    #pragma unroll
    for (int i = 0; i < CPL; i++) op[i * 64 + lane] = accv[i] * inv;
}

// ---------------- gated skip; optional fp32 / bf16 outputs ----------------
template<int CPL>   // hc = CPL*64
__global__ __launch_bounds__(256) void gate_kernel(
    const float* __restrict__ o,
    const float* __restrict__ xr, int xrN, int xrOff,
    const float* __restrict__ Wb,
    float* __restrict__ yf, bf16* __restrict__ yb, int n)
{
    const int hc = CPL * 64;
    int lane = threadIdx.x & 63;
    int row = blockIdx.x * 4 + (threadIdx.x >> 6);
    if (row >= n) return;
    const float* op = o + (size_t)row * hc;
    const float* xp = xr + (size_t)row * xrN + xrOff;
    float ov[CPL], xv[CPL], s = 0.f;
    #pragma unroll
    for (int i = 0; i < CPL; i++) {
        int c = i * 64 + lane;
        ov[i] = op[c];
        xv[i] = xp[c];
        s += ov[i] * Wb[c] + xv[i] * Wb[hc + c] + (ov[i] - xv[i]) * Wb[2 * hc + c];
    }
    #pragma unroll
    for (int off = 32; off > 0; off >>= 1) s += __shfl_xor(s, off, 64);
    float g = 1.f / (1.f + __expf(-s));
    #pragma unroll
    for (int i = 0; i < CPL; i++) {
        int c = i * 64 + lane;
        float yv = g * xv[i] + (1.f - g) * ov[i];
        if (yf) yf[(size_t)row * hc + c] = yv;
        if (yb) yb[(size_t)row * hc + c] = (bf16)yv;
    }
}

// ---------------- column stats + norm+ELU (bf16 out) ----------------
__global__ __launch_bounds__(256) void colstat_partial(
    const float* __restrict__ x, int M, float* __restrict__ ps, float* __restrict__ pss)
{
    int f = threadIdx.x;
    int b = blockIdx.x;   // 64 blocks
    float s = 0.f, ss = 0.f;
    for (int r = b; r < M; r += 64) {
        float v = x[(size_t)r * H + f];
        s += v; ss += v * v;
    }
    ps[b * H + f] = s;
    pss[b * H + f] = ss;
}

__global__ __launch_bounds__(256) void colstat_final(
    const float* __restrict__ ps, const float* __restrict__ pss, int M,
    float* __restrict__ mean, float* __restrict__ istd)
{
    int f = threadIdx.x;
    float s = 0.f, ss = 0.f;
    for (int b = 0; b < 64; b++) { s += ps[b * H + f]; ss += pss[b * H + f]; }
    float mu = s / M;
    float var = ss / M - mu * mu;
    mean[f] = mu;
    istd[f] = rsqrtf(var + 1e-5f);
}

__global__ __launch_bounds__(256) void norm_elu_bf16(
    const float* __restrict__ x, const float* __restrict__ mean,
    const float* __restrict__ istd, bf16* __restrict__ out, int total)
{
    int i = blockIdx.x * 256 + threadIdx.x;
    if (i < total) {
        int f = i & (H - 1);
        float t = (x[i] - mean[f]) * istd[f];
        out[i] = (bf16)(t > 0.f ? t : __expf(t) - 1.0f);
    }
}

// ---------------- semantic attention across the 3 relations ----------------
__global__ __launch_bounds__(256) void semantic_kernel(
    const float* __restrict__ emb,   // (3, N3, H)
    const float* __restrict__ Wo, const float* __restrict__ bo,
    const float* __restrict__ uo, const float* __restrict__ rl,
    float* __restrict__ outp)
{
    __shared__ float m_s[3][H];
    __shared__ float red[H];
    __shared__ float score_s[3];
    int n = blockIdx.x, c = threadIdx.x;
    for (int r = 0; r < 3; r++)
        m_s[r][c] = emb[((size_t)r * N3 + n) * H + c] * rl[r];
    __syncthreads();
    for (int r = 0; r < 3; r++) {
        float t = bo[c];
        for (int k2 = 0; k2 < H; k2++) t += m_s[r][k2] * Wo[k2 * H + c];
        red[c] = tanhf(t) * uo[c];
        __syncthreads();
        for (int s = 128; s > 0; s >>= 1) {
            if (c < s) red[c] += red[c + s];
            __syncthreads();
        }
        if (c == 0) score_s[r] = red[0];
        __syncthreads();
    }
    float s0 = score_s[0], s1 = score_s[1], s2 = score_s[2];
    float mx = fmaxf(s0, fmaxf(s1, s2));
    float e0 = __expf(s0 - mx), e1 = __expf(s1 - mx), e2 = __expf(s2 - mx);
    float zi = 1.0f / (e0 + e1 + e2);
    outp[(size_t)n * H + c] = (m_s[0][c] * e0 + m_s[1][c] * e1 + m_s[2][c] * e2) * zi;
}

extern "C" void kernel_launch(void* const* d_in, const int* in_sizes, int n_in,
                              void* d_out, int out_size, void* d_ws, size_t ws_size,
                              hipStream_t stream) {
    const float* features = (const float*)d_in[0];
    const int*   n_ids    = (const int*)d_in[1];
    const int*   src1     = (const int*)d_in[2];
    const int*   src2     = (const int*)d_in[4];
    const int*   src3     = (const int*)d_in[6];
    // dict order per layer: Wq, Wk, Wv, Ws, bq, bk, bv, bs, Wb
    const float* l1_Wq = (const float*)d_in[8];
    const float* l1_Wk = (const float*)d_in[9];
    const float* l1_Wv = (const float*)d_in[10];
    const float* l1_Ws = (const float*)d_in[11];
    const float* l1_bq = (const float*)d_in[12];
    const float* l1_bk = (const float*)d_in[13];
    const float* l1_bv = (const float*)d_in[14];
    const float* l1_bs = (const float*)d_in[15];
    const float* l1_Wb = (const float*)d_in[16];
    const float* l2_Wq = (const float*)d_in[17];
    const float* l2_Wk = (const float*)d_in[18];
    const float* l2_Wv = (const float*)d_in[19];
    const float* l2_Ws = (const float*)d_in[20];
    const float* l2_bq = (const float*)d_in[21];
    const float* l2_bk = (const float*)d_in[22];
    const float* l2_bv = (const float*)d_in[23];
    const float* l2_bs = (const float*)d_in[24];
    const float* l2_Wb = (const float*)d_in[25];
    const float* l3_Wq = (const float*)d_in[26];
    const float* l3_Wk = (const float*)d_in[27];
    const float* l3_Wv = (const float*)d_in[28];
    const float* l3_Ws = (const float*)d_in[29];
    const float* l3_bq = (const float*)d_in[30];
    const float* l3_bk = (const float*)d_in[31];
    const float* l3_bv = (const float*)d_in[32];
    const float* l3_bs = (const float*)d_in[33];
    const float* l3_Wb = (const float*)d_in[34];
    const float* w_omega = (const float*)d_in[35];
    const float* b_omega = (const float*)d_in[36];
    const float* u_omega = (const float*)d_in[37];
    const float* rl      = (const float*)d_in[38];

    // ---- workspace layout ----
    float* ws = (float*)d_ws;
    size_t o = 0;
    float* emb = ws + o; o += (size_t)3 * N3 * H;
    float* qs1 = ws + o; o += (size_t)N1 * 512;   // also reused as qs2 / qs3
    float* o1  = ws + o; o += (size_t)N1 * 256;   // also reused as o2 / o3
    float* x1  = ws + o; o += (size_t)N1 * 256;
    float* ps  = ws + o; o += 64 * H;
    float* pss = ws + o; o += 64 * H;
    float* mean_ = ws + o; o += H;
    float* istd  = ws + o; o += H;
    float* qs2 = qs1; float* qs3 = qs1;
    float* o2  = o1;  float* o3  = o1;

    bf16* bws = (bf16*)(ws + o);
    size_t b = 0;
    bf16* Xg  = bws + b; b += (size_t)N0 * H;
    bf16* kv1 = bws + b; b += (size_t)N0 * 512;
    // sub-aliases inside kv1 (kv1 dead after L1 attention):
    bf16* x1b = kv1;
    bf16* kv2 = x1b + (size_t)N1 * 256;
    bf16* x2b = kv2 + (size_t)N1 * 256;
    bf16* kv3 = x2b + (size_t)N2 * 128;
    // packed transposed bf16 weights, 3 relations each
    bf16* Wkv1 = bws + b; b += (size_t)3 * 512 * H;
    bf16* Wqs1 = bws + b; b += (size_t)3 * 512 * H;
    bf16* Wkv2 = bws + b; b += (size_t)3 * 256 * H;
    bf16* Wqs2 = bws + b; b += (size_t)3 * 256 * H;
    bf16* Wkv3 = bws + b; b += (size_t)3 * 512 * 128;
    bf16* Wqs3 = bws + b; b += (size_t)3 * 512 * 128;

    const float sc128 = 0.088388347648318447f;  // 1/sqrt(128)
    const float sc256 = 0.0625f;                // 1/sqrt(256)

    // ---- pack all weights (tiny) ----
    for (int r = 0; r < 3; r++) {
        pack_bt<<<512, 256, 0, stream>>>(l1_Wk + (size_t)r * H * H, l1_Wv + (size_t)r * H * H,
                                         Wkv1 + (size_t)r * 512 * H, 256, 256);
        pack_bt<<<512, 256, 0, stream>>>(l1_Wq + (size_t)r * H * H, l1_Ws + (size_t)r * H * H,
                                         Wqs1 + (size_t)r * 512 * H, 256, 256);
        pack_bt<<<256, 256, 0, stream>>>(l2_Wk + (size_t)r * H * 128, l2_Wv + (size_t)r * H * 128,
                                         Wkv2 + (size_t)r * 256 * H, 256, 128);
        pack_bt<<<256, 256, 0, stream>>>(l2_Wq + (size_t)r * H * 128, l2_Ws + (size_t)r * H * 128,
                                         Wqs2 + (size_t)r * 256 * H, 256, 128);
        pack_bt<<<512, 128, 0, stream>>>(l3_Wk + (size_t)r * 128 * H, l3_Wv + (size_t)r * 128 * H,
                                         Wkv3 + (size_t)r * 512 * 128, 128, 256);
        pack_bt<<<512, 128, 0, stream>>>(l3_Wq + (size_t)r * 128 * H, l3_Ws + (size_t)r * 128 * H,
                                         Wqs3 + (size_t)r * 512 * 128, 128, 256);
    }

    for (int r = 0; r < 3; r++) {
        gather_bf16<<<(N0 * 64 + 255) / 256, 256, 0, stream>>>(
            features, n_ids + (size_t)r * N0, Xg, N0);
        // ---- L1: din=256, heads=2, ch=128, hc=256 ----
        gemm_rr<bf16, 256><<<dim3((N0 + 255) / 256, 8), 256, 0, stream>>>(
            Xg, Wkv1 + (size_t)r * 512 * H, l1_bk + (size_t)r * H, l1_bv + (size_t)r * H, 256,
            kv1, N0, 512);
        gemm_rr<float, 256><<<dim3((N1 + 255) / 256, 8), 256, 0, stream>>>(
            Xg, Wqs1 + (size_t)r * 512 * H, l1_bq + (size_t)r * H, l1_bs + (size_t)r * H, 256,
            qs1, N1, 512);
        attn_kernel<2, 2><<<(N1 * 2 + 3) / 4, 256, 0, stream>>>(
            qs1, 512, kv1, 512, 256, src1 + (size_t)r * N1 * FAN, o1, N1, sc128);
        gate_kernel<4><<<(N1 + 3) / 4, 256, 0, stream>>>(
            o1, qs1, 512, 256, l1_Wb + (size_t)r * 3 * H, x1, (bf16*)nullptr, N1);
        colstat_partial<<<64, 256, 0, stream>>>(x1, N1, ps, pss);
        colstat_final<<<1, 256, 0, stream>>>(ps, pss, N1, mean_, istd);
        norm_elu_bf16<<<(N1 * H + 255) / 256, 256, 0, stream>>>(x1, mean_, istd, x1b, N1 * H);
        // ---- L2: din=256, heads=1, ch=128, hc=128 ----
        gemm_rr<bf16, 256><<<dim3((N1 + 255) / 256, 4), 256, 0, stream>>>(
            x1b, Wkv2 + (size_t)r * 256 * H, l2_bk + (size_t)r * 128, l2_bv + (size_t)r * 128, 128,
            kv2, N1, 256);
        gemm_rr<float, 256><<<dim3((N2 + 255) / 256, 4), 256, 0, stream>>>(
            x1b, Wqs2 + (size_t)r * 256 * H, l2_bq + (size_t)r * 128, l2_bs + (size_t)r * 128, 128,
            qs2, N2, 256);
        attn_kernel<2, 1><<<(N2 + 3) / 4, 256, 0, stream>>>(
            qs2, 256, kv2, 256, 128, src2 + (size_t)r * N2 * FAN, o2, N2, sc128);
        gate_kernel<2><<<(N2 + 3) / 4, 256, 0, stream>>>(
            o2, qs2, 256, 128, l2_Wb + (size_t)r * 384, (float*)nullptr, x2b, N2);
        // ---- L3: din=128, heads=1, ch=256, hc=256 ----
        gemm_rr<bf16, 128><<<dim3((N2 + 255) / 256, 8), 256, 0, stream>>>(
            x2b, Wkv3 + (size_t)r * 512 * 128, l3_bk + (size_t)r * H, l3_bv + (size_t)r * H, 256,
            kv3, N2, 512);
        gemm_rr<float, 128><<<dim3((N3 + 255) / 256, 8), 256, 0, stream>>>(
            x2b, Wqs3 + (size_t)r * 512 * 128, l3_bq + (size_t)r * H, l3_bs + (size_t)r * H, 256,
            qs3, N3, 512);
        attn_kernel<4, 1><<<(N3 + 3) / 4, 256, 0, stream>>>(
            qs3, 512, kv3, 512, 256, src3 + (size_t)r * N3 * FAN, o3, N3, sc256);
        gate_kernel<4><<<(N3 + 3) / 4, 256, 0, stream>>>(
            o3, qs3, 512, 256, l3_Wb + (size_t)r * 3 * H, emb + (size_t)r * N3 * H,
            (bf16*)nullptr, N3);
    }
    semantic_kernel<<<N3, 256, 0, stream>>>(emb, w_omega, b_omega, u_omega, rl, (float*)d_out);
}

// Round 4
// 992.348 us; speedup vs baseline: 2.6121x; 1.0141x over previous
//
#include <hip/hip_runtime.h>
#include <hip/hip_bf16.h>
#include <math.h>

#define H 256
#define N0 50000
#define N1 10000
#define N2 4000
#define N3 1024
#define FAN 16

typedef __hip_bfloat16 bf16;
typedef __attribute__((ext_vector_type(8))) short short8;
typedef __attribute__((ext_vector_type(4))) short short4v;
typedef __attribute__((ext_vector_type(4))) float floatx4;

typedef const __attribute__((address_space(1))) void* gas_ptr;
typedef __attribute__((address_space(3))) void* las_ptr;

__device__ __forceinline__ void load_lds16(const void* g, void* l) {
    __builtin_amdgcn_global_load_lds((gas_ptr)g, (las_ptr)l, 16, 0, 0);
}

// ---------------- LDS-A MFMA GEMM ----------------
// C[m,n] = bias[n] + sum_k A[m,k] * Bt[n,k]
// A: MxK bf16 row-major, Bt: NxK bf16 row-major. K in {128,256} (compile-time).
// Block = 512 thr (8 waves) computing 128 rows x 256 cols. Whole A-tile (128xK)
// staged ONCE in LDS via global_load_lds (16B, XOR chunk swizzle) -> no K-loop
// barriers. A frags from LDS; B frags straight from L2-resident global with
// one-kc-ahead register prefetch. 4 waves/SIMD (VGPR<=128) hides B latency.
template<typename OutT, int K>
__global__ __launch_bounds__(512, 4) void gemm_lds(
    const bf16* __restrict__ A, const bf16* __restrict__ Bt,
    const float* __restrict__ b1, const float* __restrict__ b2, int Nh,
    OutT* __restrict__ C, int M, int N)
{
    constexpr int KC = K / 32;                 // mfma k-steps
    constexpr int CPR = K / 8;                 // 16B chunks per A row
    constexpr int LOG_CPR = (K == 256) ? 5 : 4;
    constexpr int RPI = 64 / CPR;              // rows per staging issue
    constexpr int ISSUES = 16 / RPI;           // issues per wave (16 rows/wave)
    __shared__ bf16 A_s[128 * K];

    const int lane = threadIdx.x & 63;
    const int w = threadIdx.x >> 6;            // 0..7
    const int rh = w >> 2;                     // row half (0/1)
    const int cg = w & 3;                      // col group (0..3)
    const int lm = lane & 15;
    const int q = lane >> 4;
    const int mbase = blockIdx.x * 128;
    const int n0 = blockIdx.y * 256;

    // ---- stage A tile: LDS row r holds global chunks permuted by c^(r&7) ----
    {
        const int ch = lane & (CPR - 1);
        const int rsub = lane >> LOG_CPR;
        #pragma unroll
        for (int i = 0; i < ISSUES; i++) {
            int row = w * 16 + i * RPI + rsub;
            int grow = mbase + row; grow = grow < M ? grow : M - 1;
            int gch = ch ^ (row & 7);
            load_lds16(A + (size_t)grow * K + gch * 8,
                       A_s + (size_t)(w * 16 + i * RPI) * K);
        }
    }

    const bf16* bp[4];
    #pragma unroll
    for (int ni = 0; ni < 4; ni++)
        bp[ni] = Bt + (size_t)(n0 + cg * 64 + ni * 16 + lm) * K + q * 8;

    floatx4 acc[4][4];
    #pragma unroll
    for (int i = 0; i < 4; i++)
        #pragma unroll
        for (int j = 0; j < 4; j++)
            acc[i][j] = (floatx4){0.f, 0.f, 0.f, 0.f};

    __syncthreads();

    short8 bn[4];
    #pragma unroll
    for (int ni = 0; ni < 4; ni++) bn[ni] = *(const short8*)(bp[ni]);

    #pragma unroll
    for (int kc = 0; kc < KC; kc++) {
        short8 bc[4];
        #pragma unroll
        for (int ni = 0; ni < 4; ni++) bc[ni] = bn[ni];
        if (kc + 1 < KC) {
            #pragma unroll
            for (int ni = 0; ni < 4; ni++)
                bn[ni] = *(const short8*)(bp[ni] + (kc + 1) * 32);
        }
        short8 af[4];
        #pragma unroll
        for (int mi = 0; mi < 4; mi++) {
            int row = rh * 64 + mi * 16 + lm;
            af[mi] = *(const short8*)(A_s + row * K + (((kc * 4 + q) ^ (lm & 7)) * 8));
        }
        #pragma unroll
        for (int mi = 0; mi < 4; mi++)
            #pragma unroll
            for (int ni = 0; ni < 4; ni++)
                acc[mi][ni] = __builtin_amdgcn_mfma_f32_16x16x32_bf16(
                    af[mi], bc[ni], acc[mi][ni], 0, 0, 0);
    }

    // C/D layout: col = lane&15, row = (lane>>4)*4 + reg  [m89]
    if constexpr (sizeof(OutT) == 2) {
        // per-wave private transpose slice inside (now dead) A_s; one barrier.
        __syncthreads();
        bf16* stg = A_s + (size_t)w * (16 * 72);   // 16 rows x pitch 72
        #pragma unroll
        for (int p = 0; p < 4; p++) {              // p == mi
            #pragma unroll
            for (int ni = 0; ni < 4; ni++) {
                int colg = n0 + cg * 64 + ni * 16 + lm;
                float bias = (colg < Nh) ? b1[colg] : b2[colg - Nh];
                #pragma unroll
                for (int rg = 0; rg < 4; rg++)
                    stg[(q * 4 + rg) * 72 + ni * 16 + lm] = (bf16)(acc[p][ni][rg] + bias);
            }
            #pragma unroll
            for (int it = 0; it < 2; it++) {
                int rl = it * 8 + (lane >> 3);     // 0..15
                int grow = mbase + rh * 64 + p * 16 + rl;
                short8 vv = *(const short8*)(stg + rl * 72 + (lane & 7) * 8);
                if (grow < M)
                    *(short8*)(C + (size_t)grow * N + n0 + cg * 64 + (lane & 7) * 8) = vv;
            }
        }
    } else {
        #pragma unroll
        for (int ni = 0; ni < 4; ni++) {
            int colg = n0 + cg * 64 + ni * 16 + lm;
            float bias = (colg < Nh) ? b1[colg] : b2[colg - Nh];
            #pragma unroll
            for (int mi = 0; mi < 4; mi++) {
                int rb = mbase + rh * 64 + mi * 16 + q * 4;
                #pragma unroll
                for (int rg = 0; rg < 4; rg++) {
                    int rr = rb + rg;
                    if (rr < M) C[(size_t)rr * N + colg] = acc[mi][ni][rg] + bias;
                }
            }
        }
    }
}

// ---------------- gather rows of features -> bf16 (float4 in, 8B out) ----------------
__global__ __launch_bounds__(256) void gather_bf16(
    const float* __restrict__ F, const int* __restrict__ idx, bf16* __restrict__ out,
    int nrows)
{
    int t = blockIdx.x * 256 + threadIdx.x;
    int row = t >> 6;                 // wave-uniform
    if (row >= nrows) return;
    int c4 = (t & 63) * 4;
    float4 v = *(const float4*)(F + (size_t)idx[row] * H + c4);
    bf16 tmp[4] = {(bf16)v.x, (bf16)v.y, (bf16)v.z, (bf16)v.w};
    *(short4v*)(out + (size_t)row * H + c4) = *(const short4v*)tmp;
}

// ---------------- weight pack (3 relations via blockIdx.y) ----------------
__global__ void pack_bt3(const float* __restrict__ W1, const float* __restrict__ W2,
                         bf16* __restrict__ Wt, int K, int Nh)
{
    int r = blockIdx.y;
    int nn = blockIdx.x;   // 0..2*Nh-1
    int k = threadIdx.x;   // K threads
    size_t wstride = (size_t)K * Nh;
    float v = (nn < Nh) ? W1[r * wstride + (size_t)k * Nh + nn]
                        : W2[r * wstride + (size_t)k * Nh + (nn - Nh)];
    Wt[(size_t)r * 2 * wstride + (size_t)nn * K + k] = (bf16)v;
}

// ---------------- fused attention + gated skip: one wave per dst ----------------
// qs row = [q(hc) | s(hc)] fp32; kv row = [k(hc) | v(hc)] bf16.
template<int CPL, int HEADS>   // hc = CPL*64
__global__ __launch_bounds__(256) void attn_gate(
    const float* __restrict__ qs,
    const bf16* __restrict__ kv,
    const int* __restrict__ src,
    const float* __restrict__ Wb,
    float* __restrict__ yf, bf16* __restrict__ yb,
    int ndst, float scale)
{
    const int hc = CPL * 64;
    constexpr int CPLH = CPL / HEADS;
    int lane = threadIdx.x & 63;
    int d = blockIdx.x * 4 + (threadIdx.x >> 6);
    if (d >= ndst) return;
    const float* qp = qs + (size_t)d * (2 * hc);
    float qv[CPL], xv[CPL];
    #pragma unroll
    for (int i = 0; i < CPL; i++) {
        qv[i] = qp[i * 64 + lane];
        xv[i] = qp[hc + i * 64 + lane];
    }
    const int* sp = src + (size_t)d * FAN;
    int sidx[FAN];
    #pragma unroll
    for (int e = 0; e < FAN; e++) sidx[e] = sp[e];

    float ov[CPL];
    #pragma unroll
    for (int i = 0; i < CPL; i++) ov[i] = 0.f;

    #pragma unroll
    for (int h = 0; h < HEADS; h++) {
        float logit[FAN], mx = -1e30f;
        #pragma unroll
        for (int e = 0; e < FAN; e++) {
            const bf16* kp = kv + (size_t)sidx[e] * (2 * hc) + h * CPLH * 64;
            float dot = 0.f;
            #pragma unroll
            for (int i = 0; i < CPLH; i++) dot += qv[h * CPLH + i] * (float)kp[i * 64 + lane];
            #pragma unroll
            for (int off = 32; off > 0; off >>= 1) dot += __shfl_xor(dot, off, 64);
            dot *= scale;
            logit[e] = dot;
            mx = fmaxf(mx, dot);
        }
        float z = 0.f, p[FAN];
        #pragma unroll
        for (int e = 0; e < FAN; e++) { p[e] = __expf(logit[e] - mx); z += p[e]; }
        float inv = 1.f / z;
        #pragma unroll
        for (int e = 0; e < FAN; e++) {
            const bf16* vp = kv + (size_t)sidx[e] * (2 * hc) + hc + h * CPLH * 64;
            #pragma unroll
            for (int i = 0; i < CPLH; i++) ov[h * CPLH + i] += p[e] * (float)vp[i * 64 + lane];
        }
        #pragma unroll
        for (int i = 0; i < CPLH; i++) ov[h * CPLH + i] *= inv;
    }
    // gated skip
    float s = 0.f;
    #pragma unroll
    for (int i = 0; i < CPL; i++) {
        int c = i * 64 + lane;
        s += ov[i] * Wb[c] + xv[i] * Wb[hc + c] + (ov[i] - xv[i]) * Wb[2 * hc + c];
    }
    #pragma unroll
    for (int off = 32; off > 0; off >>= 1) s += __shfl_xor(s, off, 64);
    float g = 1.f / (1.f + __expf(-s));
    #pragma unroll
    for (int i = 0; i < CPL; i++) {
        int c = i * 64 + lane;
        float yv = g * xv[i] + (1.f - g) * ov[i];
        if (yf) yf[(size_t)d * hc + c] = yv;
        if (yb) yb[(size_t)d * hc + c] = (bf16)yv;
    }
}

// ---------------- column stats + fused final-reduce + norm + ELU ----------------
__global__ __launch_bounds__(256) void colstat_partial(
    const float* __restrict__ x, int M, float* __restrict__ ps, float* __restrict__ pss)
{
    int f = threadIdx.x;
    int b = blockIdx.x;   // 64 blocks
    float s = 0.f, ss = 0.f;
    for (int r = b; r < M; r += 64) {
        float v = x[(size_t)r * H + f];
        s += v; ss += v * v;
    }
    ps[b * H + f] = s;
    pss[b * H + f] = ss;
}

__global__ __launch_bounds__(256) void colfinal_norm_elu(
    const float* __restrict__ ps, const float* __restrict__ pss,
    const float* __restrict__ x, bf16* __restrict__ out, int M)
{
    int c = threadIdx.x;
    float s = 0.f, ss = 0.f;
    #pragma unroll 8
    for (int b = 0; b < 64; b++) { s += ps[b * H + c]; ss += pss[b * H + c]; }
    float mu = s / M;
    float istd = rsqrtf(ss / M - mu * mu + 1e-5f);
    for (int r = blockIdx.x; r < M; r += gridDim.x) {
        float t = (x[(size_t)r * H + c] - mu) * istd;
        out[(size_t)r * H + c] = (bf16)(t > 0.f ? t : __expf(t) - 1.0f);
    }
}

// ---------------- semantic attention across the 3 relations ----------------
__global__ __launch_bounds__(256) void semantic_kernel(
    const float* __restrict__ emb,   // (3, N3, H)
    const float* __restrict__ Wo, const float* __restrict__ bo,
    const float* __restrict__ uo, const float* __restrict__ rl,
    float* __restrict__ outp)
{
    __shared__ float m_s[3][H];
    __shared__ float red[H];
    __shared__ float score_s[3];
    int n = blockIdx.x, c = threadIdx.x;
    for (int r = 0; r < 3; r++)
        m_s[r][c] = emb[((size_t)r * N3 + n) * H + c] * rl[r];
    __syncthreads();
    for (int r = 0; r < 3; r++) {
        float t = bo[c];
        for (int k2 = 0; k2 < H; k2++) t += m_s[r][k2] * Wo[k2 * H + c];
        red[c] = tanhf(t) * uo[c];
        __syncthreads();
        for (int s = 128; s > 0; s >>= 1) {
            if (c < s) red[c] += red[c + s];
            __syncthreads();
        }
        if (c == 0) score_s[r] = red[0];
        __syncthreads();
    }
    float s0 = score_s[0], s1 = score_s[1], s2 = score_s[2];
    float mx = fmaxf(s0, fmaxf(s1, s2));
    float e0 = __expf(s0 - mx), e1 = __expf(s1 - mx), e2 = __expf(s2 - mx);
    float zi = 1.0f / (e0 + e1 + e2);
    outp[(size_t)n * H + c] = (m_s[0][c] * e0 + m_s[1][c] * e1 + m_s[2][c] * e2) * zi;
}

extern "C" void kernel_launch(void* const* d_in, const int* in_sizes, int n_in,
                              void* d_out, int out_size, void* d_ws, size_t ws_size,
                              hipStream_t stream) {
    const float* features = (const float*)d_in[0];
    const int*   n_ids    = (const int*)d_in[1];
    const int*   src1     = (const int*)d_in[2];
    const int*   src2     = (const int*)d_in[4];
    const int*   src3     = (const int*)d_in[6];
    // dict order per layer: Wq, Wk, Wv, Ws, bq, bk, bv, bs, Wb
    const float* l1_Wq = (const float*)d_in[8];
    const float* l1_Wk = (const float*)d_in[9];
    const float* l1_Wv = (const float*)d_in[10];
    const float* l1_Ws = (const float*)d_in[11];
    const float* l1_bq = (const float*)d_in[12];
    const float* l1_bk = (const float*)d_in[13];
    const float* l1_bv = (const float*)d_in[14];
    const float* l1_bs = (const float*)d_in[15];
    const float* l1_Wb = (const float*)d_in[16];
    const float* l2_Wq = (const float*)d_in[17];
    const float* l2_Wk = (const float*)d_in[18];
    const float* l2_Wv = (const float*)d_in[19];
    const float* l2_Ws = (const float*)d_in[20];
    const float* l2_bq = (const float*)d_in[21];
    const float* l2_bk = (const float*)d_in[22];
    const float* l2_bv = (const float*)d_in[23];
    const float* l2_bs = (const float*)d_in[24];
    const float* l2_Wb = (const float*)d_in[25];
    const float* l3_Wq = (const float*)d_in[26];
    const float* l3_Wk = (const float*)d_in[27];
    const float* l3_Wv = (const float*)d_in[28];
    const float* l3_Ws = (const float*)d_in[29];
    const float* l3_bq = (const float*)d_in[30];
    const float* l3_bk = (const float*)d_in[31];
    const float* l3_bv = (const float*)d_in[32];
    const float* l3_bs = (const float*)d_in[33];
    const float* l3_Wb = (const float*)d_in[34];
    const float* w_omega = (const float*)d_in[35];
    const float* b_omega = (const float*)d_in[36];
    const float* u_omega = (const float*)d_in[37];
    const float* rl      = (const float*)d_in[38];

    // ---- workspace layout ----
    float* ws = (float*)d_ws;
    size_t o = 0;
    float* emb = ws + o; o += (size_t)3 * N3 * H;
    float* qs1 = ws + o; o += (size_t)N1 * 512;   // reused as qs2 / qs3
    float* x1  = ws + o; o += (size_t)N1 * 256;
    float* ps  = ws + o; o += 64 * H;
    float* pss = ws + o; o += 64 * H;
    float* qs2 = qs1; float* qs3 = qs1;

    bf16* bws = (bf16*)(ws + o);
    size_t b = 0;
    bf16* Xg  = bws + b; b += (size_t)N0 * H;
    bf16* kv1 = bws + b; b += (size_t)N0 * 512;
    // sub-aliases inside kv1 (kv1 dead after L1 attention):
    bf16* x1b = kv1;
    bf16* kv2 = x1b + (size_t)N1 * 256;
    bf16* x2b = kv2 + (size_t)N1 * 256;
    bf16* kv3 = x2b + (size_t)N2 * 128;
    // packed transposed bf16 weights, 3 relations each
    bf16* Wkv1 = bws + b; b += (size_t)3 * 512 * H;
    bf16* Wqs1 = bws + b; b += (size_t)3 * 512 * H;
    bf16* Wkv2 = bws + b; b += (size_t)3 * 256 * H;
    bf16* Wqs2 = bws + b; b += (size_t)3 * 256 * H;
    bf16* Wkv3 = bws + b; b += (size_t)3 * 512 * 128;
    bf16* Wqs3 = bws + b; b += (size_t)3 * 512 * 128;

    const float sc128 = 0.088388347648318447f;  // 1/sqrt(128)
    const float sc256 = 0.0625f;                // 1/sqrt(256)

    // ---- pack all weights (6 dispatches, relation via blockIdx.y) ----
    pack_bt3<<<dim3(512, 3), 256, 0, stream>>>(l1_Wk, l1_Wv, Wkv1, 256, 256);
    pack_bt3<<<dim3(512, 3), 256, 0, stream>>>(l1_Wq, l1_Ws, Wqs1, 256, 256);
    pack_bt3<<<dim3(256, 3), 256, 0, stream>>>(l2_Wk, l2_Wv, Wkv2, 256, 128);
    pack_bt3<<<dim3(256, 3), 256, 0, stream>>>(l2_Wq, l2_Ws, Wqs2, 256, 128);
    pack_bt3<<<dim3(512, 3), 128, 0, stream>>>(l3_Wk, l3_Wv, Wkv3, 128, 256);
    pack_bt3<<<dim3(512, 3), 128, 0, stream>>>(l3_Wq, l3_Ws, Wqs3, 128, 256);

    for (int r = 0; r < 3; r++) {
        gather_bf16<<<(N0 * 64 + 255) / 256, 256, 0, stream>>>(
            features, n_ids + (size_t)r * N0, Xg, N0);
        // ---- L1: din=256, heads=2, ch=128, hc=256 ----
        gemm_lds<bf16, 256><<<dim3((N0 + 127) / 128, 2), 512, 0, stream>>>(
            Xg, Wkv1 + (size_t)r * 512 * H, l1_bk + (size_t)r * H, l1_bv + (size_t)r * H, 256,
            kv1, N0, 512);
        gemm_lds<float, 256><<<dim3((N1 + 127) / 128, 2), 512, 0, stream>>>(
            Xg, Wqs1 + (size_t)r * 512 * H, l1_bq + (size_t)r * H, l1_bs + (size_t)r * H, 256,
            qs1, N1, 512);
        attn_gate<4, 2><<<(N1 + 3) / 4, 256, 0, stream>>>(
            qs1, kv1, src1 + (size_t)r * N1 * FAN, l1_Wb + (size_t)r * 3 * H,
            x1, (bf16*)nullptr, N1, sc128);
        colstat_partial<<<64, 256, 0, stream>>>(x1, N1, ps, pss);
        colfinal_norm_elu<<<128, 256, 0, stream>>>(ps, pss, x1, x1b, N1);
        // ---- L2: din=256, heads=1, ch=128, hc=128 ----
        gemm_lds<bf16, 256><<<dim3((N1 + 127) / 128, 1), 512, 0, stream>>>(
            x1b, Wkv2 + (size_t)r * 256 * H, l2_bk + (size_t)r * 128, l2_bv + (size_t)r * 128, 128,
            kv2, N1, 256);
        gemm_lds<float, 256><<<dim3((N2 + 127) / 128, 1), 512, 0, stream>>>(
            x1b, Wqs2 + (size_t)r * 256 * H, l2_bq + (size_t)r * 128, l2_bs + (size_t)r * 128, 128,
            qs2, N2, 256);
        attn_gate<2, 1><<<(N2 + 3) / 4, 256, 0, stream>>>(
            qs2, kv2, src2 + (size_t)r * N2 * FAN, l2_Wb + (size_t)r * 384,
            (float*)nullptr, x2b, N2, sc128);
        // ---- L3: din=128, heads=1, ch=256, hc=256 ----
        gemm_lds<bf16, 128><<<dim3((N2 + 127) / 128, 2), 512, 0, stream>>>(
            x2b, Wkv3 + (size_t)r * 512 * 128, l3_bk + (size_t)r * H, l3_bv + (size_t)r * H, 256,
            kv3, N2, 512);
        gemm_lds<float, 128><<<dim3((N3 + 127) / 128, 2), 512, 0, stream>>>(
            x2b, Wqs3 + (size_t)r * 512 * 128, l3_bq + (size_t)r * H, l3_bs + (size_t)r * H, 256,
            qs3, N3, 512);
        attn_gate<4, 1><<<(N3 + 3) / 4, 256, 0, stream>>>(
            qs3, kv3, src3 + (size_t)r * N3 * FAN, l3_Wb + (size_t)r * 3 * H,
            emb + (size_t)r * N3 * H, (bf16*)nullptr, N3, sc256);
    }
    semantic_kernel<<<N3, 256, 0, stream>>>(emb, w_omega, b_omega, u_omega, rl, (float*)d_out);
}

// Round 5
// 663.389 us; speedup vs baseline: 3.9073x; 1.4959x over previous
//
#include <hip/hip_runtime.h>
#include <hip/hip_bf16.h>
#include <math.h>

#define H 256
#define N0 50000
#define N1 10000
#define N2 4000
#define N3 1024
#define FAN 16

typedef __hip_bfloat16 bf16;
typedef __attribute__((ext_vector_type(8))) short short8;
typedef __attribute__((ext_vector_type(4))) short short4v;
typedef __attribute__((ext_vector_type(2))) short short2v;
typedef __attribute__((ext_vector_type(4))) float floatx4;

typedef const __attribute__((address_space(1))) void* gas_ptr;
typedef __attribute__((address_space(3))) void* las_ptr;

__device__ __forceinline__ void load_lds16(const void* g, void* l) {
    __builtin_amdgcn_global_load_lds((gas_ptr)g, (las_ptr)l, 16, 0, 0);
}

__device__ __forceinline__ float2 cvt_bf2(unsigned u) {
    union { unsigned q; float f; } lo, hi;
    lo.q = u << 16; hi.q = u & 0xffff0000u;
    return make_float2(lo.f, hi.f);
}

// ---------------- LDS-A MFMA GEMM, relation-batched via blockIdx.z ----------------
// C[m,n] = bias[n] + sum_k A[m,k] * Bt[n,k];  K in {128,256}.
// 512 thr / 8 waves; 128 rows x 256 cols per block. Whole A-tile staged once via
// global_load_lds (16B, XOR chunk swizzle), zero K-loop barriers; B from L2-resident
// global with one-step register prefetch. 4 waves/SIMD.
template<typename OutT, int K>
__global__ __launch_bounds__(512, 4) void gemm_lds(
    const bf16* __restrict__ A, size_t Astr,
    const bf16* __restrict__ Bt,
    const float* __restrict__ b1, const float* __restrict__ b2, int Nh,
    OutT* __restrict__ C, size_t Cstr, int M, int N)
{
    constexpr int KC = K / 32;
    constexpr int CPR = K / 8;
    constexpr int LOG_CPR = (K == 256) ? 5 : 4;
    constexpr int RPI = 64 / CPR;
    constexpr int ISSUES = 16 / RPI;
    __shared__ bf16 A_s[128 * K];

    const int z = blockIdx.z;
    A  += (size_t)z * Astr;
    Bt += (size_t)z * N * K;
    b1 += (size_t)z * Nh;
    b2 += (size_t)z * Nh;
    C  += (size_t)z * Cstr;

    const int lane = threadIdx.x & 63;
    const int w = threadIdx.x >> 6;
    const int rh = w >> 2;
    const int cg = w & 3;
    const int lm = lane & 15;
    const int q = lane >> 4;
    const int mbase = blockIdx.x * 128;
    const int n0 = blockIdx.y * 256;

    {
        const int ch = lane & (CPR - 1);
        const int rsub = lane >> LOG_CPR;
        #pragma unroll
        for (int i = 0; i < ISSUES; i++) {
            int row = w * 16 + i * RPI + rsub;
            int grow = mbase + row; grow = grow < M ? grow : M - 1;
            int gch = ch ^ (row & 7);
            load_lds16(A + (size_t)grow * K + gch * 8,
                       A_s + (size_t)(w * 16 + i * RPI) * K);
        }
    }

    const bf16* bp[4];
    #pragma unroll
    for (int ni = 0; ni < 4; ni++)
        bp[ni] = Bt + (size_t)(n0 + cg * 64 + ni * 16 + lm) * K + q * 8;

    floatx4 acc[4][4];
    #pragma unroll
    for (int i = 0; i < 4; i++)
        #pragma unroll
        for (int j = 0; j < 4; j++)
            acc[i][j] = (floatx4){0.f, 0.f, 0.f, 0.f};

    __syncthreads();

    short8 bn[4];
    #pragma unroll
    for (int ni = 0; ni < 4; ni++) bn[ni] = *(const short8*)(bp[ni]);

    #pragma unroll
    for (int kc = 0; kc < KC; kc++) {
        short8 bc[4];
        #pragma unroll
        for (int ni = 0; ni < 4; ni++) bc[ni] = bn[ni];
        if (kc + 1 < KC) {
            #pragma unroll
            for (int ni = 0; ni < 4; ni++)
                bn[ni] = *(const short8*)(bp[ni] + (kc + 1) * 32);
        }
        short8 af[4];
        #pragma unroll
        for (int mi = 0; mi < 4; mi++) {
            int row = rh * 64 + mi * 16 + lm;
            af[mi] = *(const short8*)(A_s + row * K + (((kc * 4 + q) ^ (lm & 7)) * 8));
        }
        #pragma unroll
        for (int mi = 0; mi < 4; mi++)
            #pragma unroll
            for (int ni = 0; ni < 4; ni++)
                acc[mi][ni] = __builtin_amdgcn_mfma_f32_16x16x32_bf16(
                    af[mi], bc[ni], acc[mi][ni], 0, 0, 0);
    }

    // C/D layout: col = lane&15, row = (lane>>4)*4 + reg  [m89]
    if constexpr (sizeof(OutT) == 2) {
        __syncthreads();
        bf16* stg = A_s + (size_t)w * (16 * 72);
        #pragma unroll
        for (int p = 0; p < 4; p++) {
            #pragma unroll
            for (int ni = 0; ni < 4; ni++) {
                int colg = n0 + cg * 64 + ni * 16 + lm;
                float bias = (colg < Nh) ? b1[colg] : b2[colg - Nh];
                #pragma unroll
                for (int rg = 0; rg < 4; rg++)
                    stg[(q * 4 + rg) * 72 + ni * 16 + lm] = (bf16)(acc[p][ni][rg] + bias);
            }
            #pragma unroll
            for (int it = 0; it < 2; it++) {
                int rl = it * 8 + (lane >> 3);
                int grow = mbase + rh * 64 + p * 16 + rl;
                short8 vv = *(const short8*)(stg + rl * 72 + (lane & 7) * 8);
                if (grow < M)
                    *(short8*)(C + (size_t)grow * N + n0 + cg * 64 + (lane & 7) * 8) = vv;
            }
        }
    } else {
        #pragma unroll
        for (int ni = 0; ni < 4; ni++) {
            int colg = n0 + cg * 64 + ni * 16 + lm;
            float bias = (colg < Nh) ? b1[colg] : b2[colg - Nh];
            #pragma unroll
            for (int mi = 0; mi < 4; mi++) {
                int rb = mbase + rh * 64 + mi * 16 + q * 4;
                #pragma unroll
                for (int rg = 0; rg < 4; rg++) {
                    int rr = rb + rg;
                    if (rr < M) C[(size_t)rr * N + colg] = acc[mi][ni][rg] + bias;
                }
            }
        }
    }
}

// ---------------- gather rows of features -> bf16, relation via blockIdx.y ----------
__global__ __launch_bounds__(256) void gather_bf16(
    const float* __restrict__ F, const int* __restrict__ n_ids, bf16* __restrict__ out,
    int nrows)
{
    int z = blockIdx.y;
    const int* idx = n_ids + (size_t)z * nrows;
    bf16* o = out + (size_t)z * nrows * H;
    int t = blockIdx.x * 256 + threadIdx.x;
    int row = t >> 6;
    if (row >= nrows) return;
    int c4 = (t & 63) * 4;
    float4 v = *(const float4*)(F + (size_t)idx[row] * H + c4);
    bf16 tmp[4] = {(bf16)v.x, (bf16)v.y, (bf16)v.z, (bf16)v.w};
    *(short4v*)(o + (size_t)row * H + c4) = *(const short4v*)tmp;
}

// ---------------- weight pack (3 relations via blockIdx.y) ----------------
__global__ void pack_bt3(const float* __restrict__ W1, const float* __restrict__ W2,
                         bf16* __restrict__ Wt, int K, int Nh)
{
    int r = blockIdx.y;
    int nn = blockIdx.x;
    int k = threadIdx.x;
    size_t wstride = (size_t)K * Nh;
    float v = (nn < Nh) ? W1[r * wstride + (size_t)k * Nh + nn]
                        : W2[r * wstride + (size_t)k * Nh + (nn - Nh)];
    Wt[(size_t)r * 2 * wstride + (size_t)nn * K + k] = (bf16)v;
}

// ---------------- fused attention + gated skip, relation via blockIdx.y ----------
// Channel mapping: c = h*ch + lane*CPLH + j  (lane-contiguous -> vector loads).
// qs row = [q(hc) | s(hc)] fp32; kv row = [k(hc) | v(hc)] bf16.
template<int CPLH, int HEADS>
__global__ __launch_bounds__(256) void attn_gate(
    const float* __restrict__ qs, size_t qsStr,
    const bf16* __restrict__ kv, size_t kvStr,
    const int* __restrict__ src,
    const float* __restrict__ Wb,
    float* __restrict__ yf, size_t yfStr,
    bf16* __restrict__ yb, size_t ybStr,
    int ndst, float scale)
{
    constexpr int ch = CPLH * 64;
    constexpr int hc = HEADS * ch;
    constexpr int CPL = HEADS * CPLH;
    const int z = blockIdx.y;
    int lane = threadIdx.x & 63;
    int d = blockIdx.x * 4 + (threadIdx.x >> 6);
    if (d >= ndst) return;
    qs += (size_t)z * qsStr;
    kv += (size_t)z * kvStr;
    src += (size_t)z * ndst * FAN;
    Wb += (size_t)z * 3 * hc;

    const float* qp = qs + (size_t)d * (2 * hc);
    float qv[CPL], xv[CPL];
    #pragma unroll
    for (int h = 0; h < HEADS; h++) {
        if constexpr (CPLH == 2) {
            float2 a = *(const float2*)(qp + h * ch + lane * 2);
            float2 b = *(const float2*)(qp + hc + h * ch + lane * 2);
            qv[h * 2] = a.x; qv[h * 2 + 1] = a.y;
            xv[h * 2] = b.x; xv[h * 2 + 1] = b.y;
        } else {
            float4 a = *(const float4*)(qp + h * ch + lane * 4);
            float4 b = *(const float4*)(qp + hc + h * ch + lane * 4);
            qv[h * 4] = a.x; qv[h * 4 + 1] = a.y; qv[h * 4 + 2] = a.z; qv[h * 4 + 3] = a.w;
            xv[h * 4] = b.x; xv[h * 4 + 1] = b.y; xv[h * 4 + 2] = b.z; xv[h * 4 + 3] = b.w;
        }
    }
    const int* sp = src + (size_t)d * FAN;
    int sidx[FAN];
    #pragma unroll
    for (int e = 0; e < FAN; e++) sidx[e] = sp[e];

    float ov[CPL];
    #pragma unroll
    for (int i = 0; i < CPL; i++) ov[i] = 0.f;

    #pragma unroll
    for (int h = 0; h < HEADS; h++) {
        float logit[FAN], mx = -1e30f;
        #pragma unroll
        for (int e = 0; e < FAN; e++) {
            const bf16* kp = kv + (size_t)sidx[e] * (2 * hc) + h * ch + lane * CPLH;
            float dot;
            if constexpr (CPLH == 2) {
                float2 kf = cvt_bf2(*(const unsigned*)kp);
                dot = qv[h * 2] * kf.x + qv[h * 2 + 1] * kf.y;
            } else {
                uint2 u = *(const uint2*)kp;
                float2 k0 = cvt_bf2(u.x), k1 = cvt_bf2(u.y);
                dot = qv[h * 4] * k0.x + qv[h * 4 + 1] * k0.y
                    + qv[h * 4 + 2] * k1.x + qv[h * 4 + 3] * k1.y;
            }
            #pragma unroll
            for (int off = 32; off > 0; off >>= 1) dot += __shfl_xor(dot, off, 64);
            dot *= scale;
            logit[e] = dot;
            mx = fmaxf(mx, dot);
        }
        float zsum = 0.f, p[FAN];
        #pragma unroll
        for (int e = 0; e < FAN; e++) { p[e] = __expf(logit[e] - mx); zsum += p[e]; }
        float inv = 1.f / zsum;
        #pragma unroll
        for (int e = 0; e < FAN; e++) {
            const bf16* vp = kv + (size_t)sidx[e] * (2 * hc) + hc + h * ch + lane * CPLH;
            if constexpr (CPLH == 2) {
                float2 vf = cvt_bf2(*(const unsigned*)vp);
                ov[h * 2] += p[e] * vf.x; ov[h * 2 + 1] += p[e] * vf.y;
            } else {
                uint2 u = *(const uint2*)vp;
                float2 v0 = cvt_bf2(u.x), v1 = cvt_bf2(u.y);
                ov[h * 4] += p[e] * v0.x; ov[h * 4 + 1] += p[e] * v0.y;
                ov[h * 4 + 2] += p[e] * v1.x; ov[h * 4 + 3] += p[e] * v1.y;
            }
        }
        #pragma unroll
        for (int j = 0; j < CPLH; j++) ov[h * CPLH + j] *= inv;
    }

    // gated skip
    float s = 0.f;
    #pragma unroll
    for (int h = 0; h < HEADS; h++)
        #pragma unroll
        for (int j = 0; j < CPLH; j++) {
            int c = h * ch + lane * CPLH + j;
            int i = h * CPLH + j;
            s += ov[i] * Wb[c] + xv[i] * Wb[hc + c] + (ov[i] - xv[i]) * Wb[2 * hc + c];
        }
    #pragma unroll
    for (int off = 32; off > 0; off >>= 1) s += __shfl_xor(s, off, 64);
    float g = 1.f / (1.f + __expf(-s));

    float yv[CPL];
    #pragma unroll
    for (int i = 0; i < CPL; i++) yv[i] = g * xv[i] + (1.f - g) * ov[i];

    #pragma unroll
    for (int h = 0; h < HEADS; h++) {
        if (yf) {
            float* op = yf + (size_t)z * yfStr + (size_t)d * hc + h * ch + lane * CPLH;
            if constexpr (CPLH == 2) *(float2*)op = make_float2(yv[h * 2], yv[h * 2 + 1]);
            else *(float4*)op = make_float4(yv[h * 4], yv[h * 4 + 1], yv[h * 4 + 2], yv[h * 4 + 3]);
        }
        if (yb) {
            bf16* op = yb + (size_t)z * ybStr + (size_t)d * hc + h * ch + lane * CPLH;
            bf16 tmp[CPLH];
            #pragma unroll
            for (int j = 0; j < CPLH; j++) tmp[j] = (bf16)yv[h * CPLH + j];
            if constexpr (CPLH == 2) *(short2v*)op = *(const short2v*)tmp;
            else *(short4v*)op = *(const short4v*)tmp;
        }
    }
}

// ---------------- column stats (bf16 input), relation via blockIdx.y ----------------
__global__ __launch_bounds__(256) void colstat_partial(
    const bf16* __restrict__ x, size_t xStr, int M,
    float* __restrict__ ps, float* __restrict__ pss)
{
    int z = blockIdx.y;
    const bf16* xp = x + (size_t)z * xStr;
    int f = threadIdx.x;
    int b = blockIdx.x;   // 64
    float s = 0.f, ss = 0.f;
    for (int r = b; r < M; r += 64) {
        float v = (float)xp[(size_t)r * H + f];
        s += v; ss += v * v;
    }
    ps[((size_t)z * 64 + b) * H + f] = s;
    pss[((size_t)z * 64 + b) * H + f] = ss;
}

// final reduce + in-place norm + ELU on bf16
__global__ __launch_bounds__(256) void colfinal_norm_elu(
    const float* __restrict__ ps, const float* __restrict__ pss,
    bf16* __restrict__ x, size_t xStr, int M)
{
    int z = blockIdx.y;
    bf16* xp = x + (size_t)z * xStr;
    int c = threadIdx.x;
    float s = 0.f, ss = 0.f;
    #pragma unroll 8
    for (int b = 0; b < 64; b++) {
        s += ps[((size_t)z * 64 + b) * H + c];
        ss += pss[((size_t)z * 64 + b) * H + c];
    }
    float mu = s / M;
    float istd = rsqrtf(ss / M - mu * mu + 1e-5f);
    for (int r = blockIdx.x; r < M; r += gridDim.x) {
        float t = ((float)xp[(size_t)r * H + c] - mu) * istd;
        xp[(size_t)r * H + c] = (bf16)(t > 0.f ? t : __expf(t) - 1.0f);
    }
}

// ---------------- semantic attention across the 3 relations ----------------
__global__ __launch_bounds__(256) void semantic_kernel(
    const float* __restrict__ emb,   // (3, N3, H)
    const float* __restrict__ Wo, const float* __restrict__ bo,
    const float* __restrict__ uo, const float* __restrict__ rl,
    float* __restrict__ outp)
{
    __shared__ float m_s[3][H];
    __shared__ float red[H];
    __shared__ float score_s[3];
    int n = blockIdx.x, c = threadIdx.x;
    for (int r = 0; r < 3; r++)
        m_s[r][c] = emb[((size_t)r * N3 + n) * H + c] * rl[r];
    __syncthreads();
    for (int r = 0; r < 3; r++) {
        float t = bo[c];
        for (int k2 = 0; k2 < H; k2++) t += m_s[r][k2] * Wo[k2 * H + c];
        red[c] = tanhf(t) * uo[c];
        __syncthreads();
        for (int s = 128; s > 0; s >>= 1) {
            if (c < s) red[c] += red[c + s];
            __syncthreads();
        }
        if (c == 0) score_s[r] = red[0];
        __syncthreads();
    }
    float s0 = score_s[0], s1 = score_s[1], s2 = score_s[2];
    float mx = fmaxf(s0, fmaxf(s1, s2));
    float e0 = __expf(s0 - mx), e1 = __expf(s1 - mx), e2 = __expf(s2 - mx);
    float zi = 1.0f / (e0 + e1 + e2);
    outp[(size_t)n * H + c] = (m_s[0][c] * e0 + m_s[1][c] * e1 + m_s[2][c] * e2) * zi;
}

extern "C" void kernel_launch(void* const* d_in, const int* in_sizes, int n_in,
                              void* d_out, int out_size, void* d_ws, size_t ws_size,
                              hipStream_t stream) {
    const float* features = (const float*)d_in[0];
    const int*   n_ids    = (const int*)d_in[1];
    const int*   src1     = (const int*)d_in[2];
    const int*   src2     = (const int*)d_in[4];
    const int*   src3     = (const int*)d_in[6];
    const float* l1_Wq = (const float*)d_in[8];
    const float* l1_Wk = (const float*)d_in[9];
    const float* l1_Wv = (const float*)d_in[10];
    const float* l1_Ws = (const float*)d_in[11];
    const float* l1_bq = (const float*)d_in[12];
    const float* l1_bk = (const float*)d_in[13];
    const float* l1_bv = (const float*)d_in[14];
    const float* l1_bs = (const float*)d_in[15];
    const float* l1_Wb = (const float*)d_in[16];
    const float* l2_Wq = (const float*)d_in[17];
    const float* l2_Wk = (const float*)d_in[18];
    const float* l2_Wv = (const float*)d_in[19];
    const float* l2_Ws = (const float*)d_in[20];
    const float* l2_bq = (const float*)d_in[21];
    const float* l2_bk = (const float*)d_in[22];
    const float* l2_bv = (const float*)d_in[23];
    const float* l2_bs = (const float*)d_in[24];
    const float* l2_Wb = (const float*)d_in[25];
    const float* l3_Wq = (const float*)d_in[26];
    const float* l3_Wk = (const float*)d_in[27];
    const float* l3_Wv = (const float*)d_in[28];
    const float* l3_Ws = (const float*)d_in[29];
    const float* l3_bq = (const float*)d_in[30];
    const float* l3_bk = (const float*)d_in[31];
    const float* l3_bv = (const float*)d_in[32];
    const float* l3_bs = (const float*)d_in[33];
    const float* l3_Wb = (const float*)d_in[34];
    const float* w_omega = (const float*)d_in[35];
    const float* b_omega = (const float*)d_in[36];
    const float* u_omega = (const float*)d_in[37];
    const float* rl      = (const float*)d_in[38];

    // ---- workspace layout: per-relation buffers (relations run concurrently) ----
    float* ws = (float*)d_ws;
    size_t o = 0;
    float* emb = ws + o; o += (size_t)3 * N3 * H;         //  3.1 MB
    float* qs1 = ws + o; o += (size_t)3 * N1 * 512;       // 61.4 MB
    float* qs2 = ws + o; o += (size_t)3 * N2 * 256;       // 12.3 MB
    float* qs3 = ws + o; o += (size_t)3 * N3 * 512;       //  6.3 MB
    float* ps  = ws + o; o += (size_t)3 * 64 * H;
    float* pss = ws + o; o += (size_t)3 * 64 * H;

    bf16* bws = (bf16*)(ws + o);
    size_t b = 0;
    bf16* Xg  = bws + b; b += (size_t)3 * N0 * H;         //  76.8 MB
    bf16* kv1 = bws + b; b += (size_t)3 * N0 * 512;       // 153.6 MB
    bf16* x1b = bws + b; b += (size_t)3 * N1 * 256;       //  15.4 MB
    bf16* kv2 = bws + b; b += (size_t)3 * N1 * 256;       //  15.4 MB
    bf16* x2b = bws + b; b += (size_t)3 * N2 * 128;       //   3.1 MB
    bf16* kv3 = bws + b; b += (size_t)3 * N2 * 512;       //  12.3 MB
    bf16* Wkv1 = bws + b; b += (size_t)3 * 512 * H;
    bf16* Wqs1 = bws + b; b += (size_t)3 * 512 * H;
    bf16* Wkv2 = bws + b; b += (size_t)3 * 256 * H;
    bf16* Wqs2 = bws + b; b += (size_t)3 * 256 * H;
    bf16* Wkv3 = bws + b; b += (size_t)3 * 512 * 128;
    bf16* Wqs3 = bws + b; b += (size_t)3 * 512 * 128;
    // total ≈ 363 MB (< allocated ~409 MB per fill counter)

    const float sc128 = 0.088388347648318447f;  // 1/sqrt(128)
    const float sc256 = 0.0625f;                // 1/sqrt(256)

    // ---- pack weights (6 dispatches) ----
    pack_bt3<<<dim3(512, 3), 256, 0, stream>>>(l1_Wk, l1_Wv, Wkv1, 256, 256);
    pack_bt3<<<dim3(512, 3), 256, 0, stream>>>(l1_Wq, l1_Ws, Wqs1, 256, 256);
    pack_bt3<<<dim3(256, 3), 256, 0, stream>>>(l2_Wk, l2_Wv, Wkv2, 256, 128);
    pack_bt3<<<dim3(256, 3), 256, 0, stream>>>(l2_Wq, l2_Ws, Wqs2, 256, 128);
    pack_bt3<<<dim3(512, 3), 128, 0, stream>>>(l3_Wk, l3_Wv, Wkv3, 128, 256);
    pack_bt3<<<dim3(512, 3), 128, 0, stream>>>(l3_Wq, l3_Ws, Wqs3, 128, 256);

    // ---- gather (all relations) ----
    gather_bf16<<<dim3((N0 * 64 + 255) / 256, 3), 256, 0, stream>>>(
        features, n_ids, Xg, N0);

    // ---- L1: din=256, heads=2, ch=128, hc=256 ----
    gemm_lds<bf16, 256><<<dim3((N0 + 127) / 128, 2, 3), 512, 0, stream>>>(
        Xg, (size_t)N0 * H, Wkv1, l1_bk, l1_bv, 256, kv1, (size_t)N0 * 512, N0, 512);
    gemm_lds<float, 256><<<dim3((N1 + 127) / 128, 2, 3), 512, 0, stream>>>(
        Xg, (size_t)N0 * H, Wqs1, l1_bq, l1_bs, 256, qs1, (size_t)N1 * 512, N1, 512);
    attn_gate<2, 2><<<dim3((N1 + 3) / 4, 3), 256, 0, stream>>>(
        qs1, (size_t)N1 * 512, kv1, (size_t)N0 * 512, src1, l1_Wb,
        (float*)nullptr, 0, x1b, (size_t)N1 * 256, N1, sc128);
    colstat_partial<<<dim3(64, 3), 256, 0, stream>>>(x1b, (size_t)N1 * 256, N1, ps, pss);
    colfinal_norm_elu<<<dim3(128, 3), 256, 0, stream>>>(ps, pss, x1b, (size_t)N1 * 256, N1);

    // ---- L2: din=256, heads=1, ch=128, hc=128 ----
    gemm_lds<bf16, 256><<<dim3((N1 + 127) / 128, 1, 3), 512, 0, stream>>>(
        x1b, (size_t)N1 * 256, Wkv2, l2_bk, l2_bv, 128, kv2, (size_t)N1 * 256, N1, 256);
    gemm_lds<float, 256><<<dim3((N2 + 127) / 128, 1, 3), 512, 0, stream>>>(
        x1b, (size_t)N1 * 256, Wqs2, l2_bq, l2_bs, 128, qs2, (size_t)N2 * 256, N2, 256);
    attn_gate<2, 1><<<dim3((N2 + 3) / 4, 3), 256, 0, stream>>>(
        qs2, (size_t)N2 * 256, kv2, (size_t)N1 * 256, src2, l2_Wb,
        (float*)nullptr, 0, x2b, (size_t)N2 * 128, N2, sc128);

    // ---- L3: din=128, heads=1, ch=256, hc=256 ----
    gemm_lds<bf16, 128><<<dim3((N2 + 127) / 128, 2, 3), 512, 0, stream>>>(
        x2b, (size_t)N2 * 128, Wkv3, l3_bk, l3_bv, 256, kv3, (size_t)N2 * 512, N2, 512);
    gemm_lds<float, 128><<<dim3((N3 + 127) / 128, 2, 3), 512, 0, stream>>>(
        x2b, (size_t)N2 * 128, Wqs3, l3_bq, l3_bs, 256, qs3, (size_t)N3 * 512, N3, 512);
    attn_gate<4, 1><<<dim3((N3 + 3) / 4, 3), 256, 0, stream>>>(
        qs3, (size_t)N3 * 512, kv3, (size_t)N2 * 512, src3, l3_Wb,
        emb, (size_t)N3 * H, (bf16*)nullptr, 0, N3, sc256);

    semantic_kernel<<<N3, 256, 0, stream>>>(emb, w_omega, b_omega, u_omega, rl, (float*)d_out);
}

// Round 6
// 612.737 us; speedup vs baseline: 4.2303x; 1.0827x over previous
//
#include <hip/hip_runtime.h>
#include <hip/hip_bf16.h>
#include <math.h>

#define H 256
#define N0 50000
#define N1 10000
#define N2 4000
#define N3 1024
#define FAN 16

typedef __hip_bfloat16 bf16;
typedef __attribute__((ext_vector_type(8))) short short8;
typedef __attribute__((ext_vector_type(4))) short short4v;
typedef __attribute__((ext_vector_type(2))) short short2v;
typedef __attribute__((ext_vector_type(4))) float floatx4;

typedef const __attribute__((address_space(1))) void* gas_ptr;
typedef __attribute__((address_space(3))) void* las_ptr;

__device__ __forceinline__ void load_lds16(const void* g, void* l) {
    __builtin_amdgcn_global_load_lds((gas_ptr)g, (las_ptr)l, 16, 0, 0);
}

__device__ __forceinline__ float2 cvt_bf2(unsigned u) {
    union { unsigned q; float f; } lo, hi;
    lo.q = u << 16; hi.q = u & 0xffff0000u;
    return make_float2(lo.f, hi.f);
}

// ---------------- dual-output LDS-A MFMA GEMM ----------------
// One dispatch computes BOTH the kv GEMM (bf16 out) and qs GEMM (fp32 out) of a
// layer: grid.x < nbKV -> kv blocks, else qs blocks (block-uniform branch).
// Tile 64 rows x 256 cols, 256 thr (4 waves, each 64x64 = 4x4 mfma tiles).
// A-tile (64xK bf16 <= 32 KB) staged once via global_load_lds w/ XOR chunk
// swizzle -> no K-loop barriers; 4 blocks/CU resident (vs 2 at 128-row tiles).
// B from L2-resident global with one-step register prefetch.
template<int K>
__global__ __launch_bounds__(256, 4) void gemm_dual(
    const bf16* __restrict__ A, size_t Astr,
    const bf16* __restrict__ BtKV, const bf16* __restrict__ BtQS,
    const float* __restrict__ bk, const float* __restrict__ bv,
    const float* __restrict__ bq, const float* __restrict__ bs, int Nh,
    bf16* __restrict__ Ckv, size_t CkvStr, int Mkv,
    float* __restrict__ Cqs, size_t CqsStr, int Mqs,
    int nbKV)
{
    constexpr int KC = K / 32;
    constexpr int CPR = K / 8;                  // 16B chunks per row
    constexpr int LOG_CPR = (K == 256) ? 5 : 4;
    constexpr int RPI = 64 / CPR;               // rows per staging issue
    constexpr int ISSUES = 16 / RPI;            // per wave (16 rows/wave)
    const int N = 2 * Nh;
    __shared__ bf16 A_s[64 * K];

    const int z = blockIdx.z;
    const bool isKV = (int)blockIdx.x < nbKV;
    const int bx = isKV ? blockIdx.x : blockIdx.x - nbKV;
    const int M = isKV ? Mkv : Mqs;
    const bf16* Bt = (isKV ? BtKV : BtQS) + (size_t)z * N * K;
    const float* b1 = (isKV ? bk : bq) + (size_t)z * Nh;
    const float* b2 = (isKV ? bv : bs) + (size_t)z * Nh;
    A += (size_t)z * Astr;

    const int lane = threadIdx.x & 63;
    const int w = threadIdx.x >> 6;             // 0..3 (col group)
    const int lm = lane & 15;
    const int q = lane >> 4;
    const int mbase = bx * 64;
    const int n0 = blockIdx.y * 256;

    // ---- stage A tile (64 x K): LDS row r holds chunks permuted by c^(r&7) ----
    {
        const int ch = lane & (CPR - 1);
        const int rsub = lane >> LOG_CPR;
        #pragma unroll
        for (int i = 0; i < ISSUES; i++) {
            int row = w * 16 + i * RPI + rsub;
            int grow = mbase + row; grow = grow < M ? grow : M - 1;
            int gch = ch ^ (row & 7);
            load_lds16(A + (size_t)grow * K + gch * 8,
                       A_s + (size_t)(w * 16 + i * RPI) * K);
        }
    }

    const bf16* bp[4];
    #pragma unroll
    for (int ni = 0; ni < 4; ni++)
        bp[ni] = Bt + (size_t)(n0 + w * 64 + ni * 16 + lm) * K + q * 8;

    floatx4 acc[4][4];
    #pragma unroll
    for (int i = 0; i < 4; i++)
        #pragma unroll
        for (int j = 0; j < 4; j++)
            acc[i][j] = (floatx4){0.f, 0.f, 0.f, 0.f};

    __syncthreads();

    short8 bn[4];
    #pragma unroll
    for (int ni = 0; ni < 4; ni++) bn[ni] = *(const short8*)(bp[ni]);

    #pragma unroll
    for (int kc = 0; kc < KC; kc++) {
        short8 bc[4];
        #pragma unroll
        for (int ni = 0; ni < 4; ni++) bc[ni] = bn[ni];
        if (kc + 1 < KC) {
            #pragma unroll
            for (int ni = 0; ni < 4; ni++)
                bn[ni] = *(const short8*)(bp[ni] + (kc + 1) * 32);
        }
        short8 af[4];
        #pragma unroll
        for (int mi = 0; mi < 4; mi++) {
            int row = mi * 16 + lm;
            af[mi] = *(const short8*)(A_s + row * K + (((kc * 4 + q) ^ (lm & 7)) * 8));
        }
        #pragma unroll
        for (int mi = 0; mi < 4; mi++)
            #pragma unroll
            for (int ni = 0; ni < 4; ni++)
                acc[mi][ni] = __builtin_amdgcn_mfma_f32_16x16x32_bf16(
                    af[mi], bc[ni], acc[mi][ni], 0, 0, 0);
    }

    // C/D layout: col = lane&15, row = (lane>>4)*4 + reg  [m89]
    if (isKV) {
        bf16* C = Ckv + (size_t)z * CkvStr;
        __syncthreads();                        // A_s dead; reuse as transpose stage
        bf16* stg = A_s + (size_t)w * (16 * 72);
        #pragma unroll
        for (int p = 0; p < 4; p++) {           // p == mi
            #pragma unroll
            for (int ni = 0; ni < 4; ni++) {
                int colg = n0 + w * 64 + ni * 16 + lm;
                float bias = (colg < Nh) ? b1[colg] : b2[colg - Nh];
                #pragma unroll
                for (int rg = 0; rg < 4; rg++)
                    stg[(q * 4 + rg) * 72 + ni * 16 + lm] = (bf16)(acc[p][ni][rg] + bias);
            }
            #pragma unroll
            for (int it = 0; it < 2; it++) {
                int rl = it * 8 + (lane >> 3);
                int grow = mbase + p * 16 + rl;
                short8 vv = *(const short8*)(stg + rl * 72 + (lane & 7) * 8);
                if (grow < M)
                    *(short8*)(C + (size_t)grow * N + n0 + w * 64 + (lane & 7) * 8) = vv;
            }
        }
    } else {
        float* C = Cqs + (size_t)z * CqsStr;
        #pragma unroll
        for (int ni = 0; ni < 4; ni++) {
            int colg = n0 + w * 64 + ni * 16 + lm;
            float bias = (colg < Nh) ? b1[colg] : b2[colg - Nh];
            #pragma unroll
            for (int mi = 0; mi < 4; mi++) {
                int rb = mbase + mi * 16 + q * 4;
                #pragma unroll
                for (int rg = 0; rg < 4; rg++) {
                    int rr = rb + rg;
                    if (rr < M) C[(size_t)rr * N + colg] = acc[mi][ni][rg] + bias;
                }
            }
        }
    }
}

// ---------------- gather rows of features -> bf16, relation via blockIdx.y ----------
__global__ __launch_bounds__(256) void gather_bf16(
    const float* __restrict__ F, const int* __restrict__ n_ids, bf16* __restrict__ out,
    int nrows)
{
    int z = blockIdx.y;
    const int* idx = n_ids + (size_t)z * nrows;
    bf16* o = out + (size_t)z * nrows * H;
    int t = blockIdx.x * 256 + threadIdx.x;
    int row = t >> 6;
    if (row >= nrows) return;
    int c4 = (t & 63) * 4;
    float4 v = *(const float4*)(F + (size_t)idx[row] * H + c4);
    bf16 tmp[4] = {(bf16)v.x, (bf16)v.y, (bf16)v.z, (bf16)v.w};
    *(short4v*)(o + (size_t)row * H + c4) = *(const short4v*)tmp;
}

// ---------------- all weight packs in ONE dispatch (job via blockIdx.z) ----------
__global__ __launch_bounds__(256) void pack_all(
    const float* __restrict__ l1_Wk, const float* __restrict__ l1_Wv,
    const float* __restrict__ l1_Wq, const float* __restrict__ l1_Ws,
    const float* __restrict__ l2_Wk, const float* __restrict__ l2_Wv,
    const float* __restrict__ l2_Wq, const float* __restrict__ l2_Ws,
    const float* __restrict__ l3_Wk, const float* __restrict__ l3_Wv,
    const float* __restrict__ l3_Wq, const float* __restrict__ l3_Ws,
    bf16* __restrict__ Wkv1, bf16* __restrict__ Wqs1,
    bf16* __restrict__ Wkv2, bf16* __restrict__ Wqs2,
    bf16* __restrict__ Wkv3, bf16* __restrict__ Wqs3)
{
    int job = blockIdx.z, r = blockIdx.y, nn = blockIdx.x, k = threadIdx.x;
    const float *W1, *W2; bf16* Wt; int K, Nh;
    switch (job) {
        case 0: W1 = l1_Wk; W2 = l1_Wv; Wt = Wkv1; K = 256; Nh = 256; break;
        case 1: W1 = l1_Wq; W2 = l1_Ws; Wt = Wqs1; K = 256; Nh = 256; break;
        case 2: W1 = l2_Wk; W2 = l2_Wv; Wt = Wkv2; K = 256; Nh = 128; break;
        case 3: W1 = l2_Wq; W2 = l2_Ws; Wt = Wqs2; K = 256; Nh = 128; break;
        case 4: W1 = l3_Wk; W2 = l3_Wv; Wt = Wkv3; K = 128; Nh = 256; break;
        default: W1 = l3_Wq; W2 = l3_Ws; Wt = Wqs3; K = 128; Nh = 256; break;
    }
    if (nn >= 2 * Nh || k >= K) return;
    size_t wstride = (size_t)K * Nh;
    float v = (nn < Nh) ? W1[(size_t)r * wstride + (size_t)k * Nh + nn]
                        : W2[(size_t)r * wstride + (size_t)k * Nh + (nn - Nh)];
    Wt[(size_t)r * 2 * wstride + (size_t)nn * K + k] = (bf16)v;
}

// ---------------- fused attention + gated skip ----------------
// Canonical lane-contiguous channel map: c = lane*CPL + j. Head h owns lanes
// [h*LPH,(h+1)*LPH); per-head dot = sub-wave xor-reduction (softmax replicated
// within the head's lane group, which is exactly what v-accumulation needs).
// qs row = [q(hc)|s(hc)] fp32; kv row = [k(hc)|v(hc)] bf16.
template<int CPL, int HEADS>   // hc = CPL*64
__global__ __launch_bounds__(256) void attn_gate(
    const float* __restrict__ qs, size_t qsStr,
    const bf16* __restrict__ kv, size_t kvStr,
    const int* __restrict__ src,
    const float* __restrict__ Wb,
    float* __restrict__ yf, size_t yfStr,
    bf16* __restrict__ yb, size_t ybStr,
    int ndst, float scale)
{
    constexpr int hc = CPL * 64;
    constexpr int LPH = 64 / HEADS;
    const int z = blockIdx.y;
    int lane = threadIdx.x & 63;
    int d = blockIdx.x * 4 + (threadIdx.x >> 6);
    if (d >= ndst) return;
    qs += (size_t)z * qsStr;
    kv += (size_t)z * kvStr;
    src += (size_t)z * ndst * FAN;
    Wb += (size_t)z * 3 * hc;

    const float* qp = qs + (size_t)d * (2 * hc) + lane * CPL;
    float qv[CPL], xv[CPL];
    if constexpr (CPL == 2) {
        float2 a = *(const float2*)qp;
        float2 b = *(const float2*)(qp + hc);
        qv[0] = a.x; qv[1] = a.y; xv[0] = b.x; xv[1] = b.y;
    } else {
        float4 a = *(const float4*)qp;
        float4 b = *(const float4*)(qp + hc);
        qv[0] = a.x; qv[1] = a.y; qv[2] = a.z; qv[3] = a.w;
        xv[0] = b.x; xv[1] = b.y; xv[2] = b.z; xv[3] = b.w;
    }
    const int* sp = src + (size_t)d * FAN;
    int sidx[FAN];
    #pragma unroll
    for (int e = 0; e < FAN; e++) sidx[e] = sp[e];

    // partial dots (all k loads issued before the shuffle phase)
    float part[FAN];
    #pragma unroll
    for (int e = 0; e < FAN; e++) {
        const bf16* kp = kv + (size_t)sidx[e] * (2 * hc) + lane * CPL;
        if constexpr (CPL == 2) {
            float2 kf = cvt_bf2(*(const unsigned*)kp);
            part[e] = qv[0] * kf.x + qv[1] * kf.y;
        } else {
            uint2 u = *(const uint2*)kp;
            float2 k0 = cvt_bf2(u.x), k1 = cvt_bf2(u.y);
            part[e] = qv[0] * k0.x + qv[1] * k0.y + qv[2] * k1.x + qv[3] * k1.y;
        }
    }
    float logit[FAN], mx = -1e30f;
    #pragma unroll
    for (int e = 0; e < FAN; e++) {
        float dt = part[e];
        #pragma unroll
        for (int off = LPH / 2; off > 0; off >>= 1) dt += __shfl_xor(dt, off, 64);
        dt *= scale;
        logit[e] = dt;
        mx = fmaxf(mx, dt);
    }
    float zsum = 0.f, p[FAN];
    #pragma unroll
    for (int e = 0; e < FAN; e++) { p[e] = __expf(logit[e] - mx); zsum += p[e]; }
    float inv = 1.f / zsum;

    float ov[CPL];
    #pragma unroll
    for (int j = 0; j < CPL; j++) ov[j] = 0.f;
    #pragma unroll
    for (int e = 0; e < FAN; e++) {
        const bf16* vp = kv + (size_t)sidx[e] * (2 * hc) + hc + lane * CPL;
        if constexpr (CPL == 2) {
            float2 vf = cvt_bf2(*(const unsigned*)vp);
            ov[0] += p[e] * vf.x; ov[1] += p[e] * vf.y;
        } else {
            uint2 u = *(const uint2*)vp;
            float2 v0 = cvt_bf2(u.x), v1 = cvt_bf2(u.y);
            ov[0] += p[e] * v0.x; ov[1] += p[e] * v0.y;
            ov[2] += p[e] * v1.x; ov[3] += p[e] * v1.y;
        }
    }
    #pragma unroll
    for (int j = 0; j < CPL; j++) ov[j] *= inv;

    // gated skip
    float s = 0.f;
    #pragma unroll
    for (int j = 0; j < CPL; j++) {
        int c = lane * CPL + j;
        s += ov[j] * Wb[c] + xv[j] * Wb[hc + c] + (ov[j] - xv[j]) * Wb[2 * hc + c];
    }
    #pragma unroll
    for (int off = 32; off > 0; off >>= 1) s += __shfl_xor(s, off, 64);
    float g = 1.f / (1.f + __expf(-s));

    float yv[CPL];
    #pragma unroll
    for (int j = 0; j < CPL; j++) yv[j] = g * xv[j] + (1.f - g) * ov[j];

    if (yf) {
        float* op = yf + (size_t)z * yfStr + (size_t)d * hc + lane * CPL;
        if constexpr (CPL == 2) *(float2*)op = make_float2(yv[0], yv[1]);
        else *(float4*)op = make_float4(yv[0], yv[1], yv[2], yv[3]);
    }
    if (yb) {
        bf16* op = yb + (size_t)z * ybStr + (size_t)d * hc + lane * CPL;
        bf16 tmp[CPL];
        #pragma unroll
        for (int j = 0; j < CPL; j++) tmp[j] = (bf16)yv[j];
        if constexpr (CPL == 2) *(short2v*)op = *(const short2v*)tmp;
        else *(short4v*)op = *(const short4v*)tmp;
    }
}

// ---------------- column stats (bf16 input), relation via blockIdx.y ----------------
__global__ __launch_bounds__(256) void colstat_partial(
    const bf16* __restrict__ x, size_t xStr, int M,
    float* __restrict__ ps, float* __restrict__ pss)
{
    int z = blockIdx.y;
    const bf16* xp = x + (size_t)z * xStr;
    int f = threadIdx.x;
    int b = blockIdx.x;   // 64
    float s = 0.f, ss = 0.f;
    for (int r = b; r < M; r += 64) {
        float v = (float)xp[(size_t)r * H + f];
        s += v; ss += v * v;
    }
    ps[((size_t)z * 64 + b) * H + f] = s;
    pss[((size_t)z * 64 + b) * H + f] = ss;
}

__global__ __launch_bounds__(256) void colfinal_norm_elu(
    const float* __restrict__ ps, const float* __restrict__ pss,
    bf16* __restrict__ x, size_t xStr, int M)
{
    int z = blockIdx.y;
    bf16* xp = x + (size_t)z * xStr;
    int c = threadIdx.x;
    float s = 0.f, ss = 0.f;
    #pragma unroll 8
    for (int b = 0; b < 64; b++) {
        s += ps[((size_t)z * 64 + b) * H + c];
        ss += pss[((size_t)z * 64 + b) * H + c];
    }
    float mu = s / M;
    float istd = rsqrtf(ss / M - mu * mu + 1e-5f);
    for (int r = blockIdx.x; r < M; r += gridDim.x) {
        float t = ((float)xp[(size_t)r * H + c] - mu) * istd;
        xp[(size_t)r * H + c] = (bf16)(t > 0.f ? t : __expf(t) - 1.0f);
    }
}

// ---------------- semantic attention across the 3 relations ----------------
__global__ __launch_bounds__(256) void semantic_kernel(
    const float* __restrict__ emb,   // (3, N3, H)
    const float* __restrict__ Wo, const float* __restrict__ bo,
    const float* __restrict__ uo, const float* __restrict__ rl,
    float* __restrict__ outp)
{
    __shared__ float m_s[3][H];
    __shared__ float red[H];
    __shared__ float score_s[3];
    int n = blockIdx.x, c = threadIdx.x;
    for (int r = 0; r < 3; r++)
        m_s[r][c] = emb[((size_t)r * N3 + n) * H + c] * rl[r];
    __syncthreads();
    for (int r = 0; r < 3; r++) {
        float t = bo[c];
        for (int k2 = 0; k2 < H; k2++) t += m_s[r][k2] * Wo[k2 * H + c];
        red[c] = tanhf(t) * uo[c];
        __syncthreads();
        for (int s = 128; s > 0; s >>= 1) {
            if (c < s) red[c] += red[c + s];
            __syncthreads();
        }
        if (c == 0) score_s[r] = red[0];
        __syncthreads();
    }
    float s0 = score_s[0], s1 = score_s[1], s2 = score_s[2];
    float mx = fmaxf(s0, fmaxf(s1, s2));
    float e0 = __expf(s0 - mx), e1 = __expf(s1 - mx), e2 = __expf(s2 - mx);
    float zi = 1.0f / (e0 + e1 + e2);
    outp[(size_t)n * H + c] = (m_s[0][c] * e0 + m_s[1][c] * e1 + m_s[2][c] * e2) * zi;
}

extern "C" void kernel_launch(void* const* d_in, const int* in_sizes, int n_in,
                              void* d_out, int out_size, void* d_ws, size_t ws_size,
                              hipStream_t stream) {
    const float* features = (const float*)d_in[0];
    const int*   n_ids    = (const int*)d_in[1];
    const int*   src1     = (const int*)d_in[2];
    const int*   src2     = (const int*)d_in[4];
    const int*   src3     = (const int*)d_in[6];
    const float* l1_Wq = (const float*)d_in[8];
    const float* l1_Wk = (const float*)d_in[9];
    const float* l1_Wv = (const float*)d_in[10];
    const float* l1_Ws = (const float*)d_in[11];
    const float* l1_bq = (const float*)d_in[12];
    const float* l1_bk = (const float*)d_in[13];
    const float* l1_bv = (const float*)d_in[14];
    const float* l1_bs = (const float*)d_in[15];
    const float* l1_Wb = (const float*)d_in[16];
    const float* l2_Wq = (const float*)d_in[17];
    const float* l2_Wk = (const float*)d_in[18];
    const float* l2_Wv = (const float*)d_in[19];
    const float* l2_Ws = (const float*)d_in[20];
    const float* l2_bq = (const float*)d_in[21];
    const float* l2_bk = (const float*)d_in[22];
    const float* l2_bv = (const float*)d_in[23];
    const float* l2_bs = (const float*)d_in[24];
    const float* l2_Wb = (const float*)d_in[25];
    const float* l3_Wq = (const float*)d_in[26];
    const float* l3_Wk = (const float*)d_in[27];
    const float* l3_Wv = (const float*)d_in[28];
    const float* l3_Ws = (const float*)d_in[29];
    const float* l3_bq = (const float*)d_in[30];
    const float* l3_bk = (const float*)d_in[31];
    const float* l3_bv = (const float*)d_in[32];
    const float* l3_bs = (const float*)d_in[33];
    const float* l3_Wb = (const float*)d_in[34];
    const float* w_omega = (const float*)d_in[35];
    const float* b_omega = (const float*)d_in[36];
    const float* u_omega = (const float*)d_in[37];
    const float* rl      = (const float*)d_in[38];

    // ---- workspace layout: per-relation buffers ----
    float* ws = (float*)d_ws;
    size_t o = 0;
    float* emb = ws + o; o += (size_t)3 * N3 * H;
    float* qs1 = ws + o; o += (size_t)3 * N1 * 512;
    float* qs2 = ws + o; o += (size_t)3 * N2 * 256;
    float* qs3 = ws + o; o += (size_t)3 * N3 * 512;
    float* ps  = ws + o; o += (size_t)3 * 64 * H;
    float* pss = ws + o; o += (size_t)3 * 64 * H;

    bf16* bws = (bf16*)(ws + o);
    size_t b = 0;
    bf16* Xg  = bws + b; b += (size_t)3 * N0 * H;
    bf16* kv1 = bws + b; b += (size_t)3 * N0 * 512;
    bf16* x1b = bws + b; b += (size_t)3 * N1 * 256;
    bf16* kv2 = bws + b; b += (size_t)3 * N1 * 256;
    bf16* x2b = bws + b; b += (size_t)3 * N2 * 128;
    bf16* kv3 = bws + b; b += (size_t)3 * N2 * 512;
    bf16* Wkv1 = bws + b; b += (size_t)3 * 512 * H;
    bf16* Wqs1 = bws + b; b += (size_t)3 * 512 * H;
    bf16* Wkv2 = bws + b; b += (size_t)3 * 256 * H;
    bf16* Wqs2 = bws + b; b += (size_t)3 * 256 * H;
    bf16* Wkv3 = bws + b; b += (size_t)3 * 512 * 128;
    bf16* Wqs3 = bws + b; b += (size_t)3 * 512 * 128;

    const float sc128 = 0.088388347648318447f;  // 1/sqrt(128)
    const float sc256 = 0.0625f;                // 1/sqrt(256)

    // ---- all weight packs, one dispatch ----
    pack_all<<<dim3(512, 3, 6), 256, 0, stream>>>(
        l1_Wk, l1_Wv, l1_Wq, l1_Ws, l2_Wk, l2_Wv, l2_Wq, l2_Ws,
        l3_Wk, l3_Wv, l3_Wq, l3_Ws, Wkv1, Wqs1, Wkv2, Wqs2, Wkv3, Wqs3);

    // ---- gather (all relations) ----
    gather_bf16<<<dim3((N0 * 64 + 255) / 256, 3), 256, 0, stream>>>(
        features, n_ids, Xg, N0);

    // ---- L1: din=256, heads=2, ch=128, hc=256, N=512, K=256 ----
    {
        int nbKV = (N0 + 63) / 64, nbQS = (N1 + 63) / 64;
        gemm_dual<256><<<dim3(nbKV + nbQS, 2, 3), 256, 0, stream>>>(
            Xg, (size_t)N0 * H, Wkv1, Wqs1, l1_bk, l1_bv, l1_bq, l1_bs, 256,
            kv1, (size_t)N0 * 512, N0, qs1, (size_t)N1 * 512, N1, nbKV);
    }
    attn_gate<4, 2><<<dim3((N1 + 3) / 4, 3), 256, 0, stream>>>(
        qs1, (size_t)N1 * 512, kv1, (size_t)N0 * 512, src1, l1_Wb,
        (float*)nullptr, 0, x1b, (size_t)N1 * 256, N1, sc128);
    colstat_partial<<<dim3(64, 3), 256, 0, stream>>>(x1b, (size_t)N1 * 256, N1, ps, pss);
    colfinal_norm_elu<<<dim3(128, 3), 256, 0, stream>>>(ps, pss, x1b, (size_t)N1 * 256, N1);

    // ---- L2: din=256, heads=1, ch=128, hc=128, N=256, K=256 ----
    {
        int nbKV = (N1 + 63) / 64, nbQS = (N2 + 63) / 64;
        gemm_dual<256><<<dim3(nbKV + nbQS, 1, 3), 256, 0, stream>>>(
            x1b, (size_t)N1 * 256, Wkv2, Wqs2, l2_bk, l2_bv, l2_bq, l2_bs, 128,
            kv2, (size_t)N1 * 256, N1, qs2, (size_t)N2 * 256, N2, nbKV);
    }
    attn_gate<2, 1><<<dim3((N2 + 3) / 4, 3), 256, 0, stream>>>(
        qs2, (size_t)N2 * 256, kv2, (size_t)N1 * 256, src2, l2_Wb,
        (float*)nullptr, 0, x2b, (size_t)N2 * 128, N2, sc128);

    // ---- L3: din=128, heads=1, ch=256, hc=256, N=512, K=128 ----
    {
        int nbKV = (N2 + 63) / 64, nbQS = (N3 + 63) / 64;
        gemm_dual<128><<<dim3(nbKV + nbQS, 2, 3), 256, 0, stream>>>(
            x2b, (size_t)N2 * 128, Wkv3, Wqs3, l3_bk, l3_bv, l3_bq, l3_bs, 256,
            kv3, (size_t)N2 * 512, N2, qs3, (size_t)N3 * 512, N3, nbKV);
    }
    attn_gate<4, 1><<<dim3((N3 + 3) / 4, 3), 256, 0, stream>>>(
        qs3, (size_t)N3 * 512, kv3, (size_t)N2 * 512, src3, l3_Wb,
        emb, (size_t)N3 * H, (bf16*)nullptr, 0, N3, sc256);

    semantic_kernel<<<N3, 256, 0, stream>>>(emb, w_omega, b_omega, u_omega, rl, (float*)d_out);
}